// Round 17
// baseline (80.880 us; speedup 1.0000x reference)
//
#include <hip/hip_runtime.h>
#include <math.h>

constexpr int CB  = 16;
constexpr int CN  = 1024;
constexpr int CD  = 512;
constexpr int KM1 = 7;      // K_MAX + 1 candidate slots per batch
constexpr int RB  = 32;     // rows per k_attn block

typedef __attribute__((ext_vector_type(8))) short bf8;
typedef __attribute__((ext_vector_type(4))) float f32x4;
typedef __attribute__((ext_vector_type(4))) unsigned short us4;

__device__ inline float bf2f(unsigned short u) {
    union { unsigned int i; float f; } v; v.i = ((unsigned)u) << 16; return v.f;
}
__device__ inline unsigned short f2bf(float f) {
    union { unsigned int i; float f; } v; v.f = f;
    unsigned r = v.i + 0x7FFFu + ((v.i >> 16) & 1u);
    return (unsigned short)(r >> 16);
}
// packed f32->bf16 (RNE) via HW instruction
__device__ inline unsigned int cvtpk(float lo, float hi) {
    unsigned int r;
    asm("v_cvt_pk_bf16_f32 %0, %1, %2" : "=v"(r) : "v"(lo), "v"(hi));
    return r;
}
__device__ inline bf8 pack8(float4 x, float4 y) {
    union { bf8 v; unsigned int u[4]; } r;
    r.u[0] = cvtpk(x.x, x.y); r.u[1] = cvtpk(x.z, x.w);
    r.u[2] = cvtpk(y.x, y.y); r.u[3] = cvtpk(y.z, y.w);
    return r.v;
}
__device__ inline us4 pack4(float4 x) {
    union { us4 v; unsigned int u[2]; } r;
    r.u[0] = cvtpk(x.x, x.y); r.u[1] = cvtpk(x.z, x.w);
    return r.v;
}

// ---------------------------------------------------------------------------
// Kernel PRE: blocks 0..15 top-7 (wave-parallel packed-min) |
// 16..143 transW | 144 computeK.
// ---------------------------------------------------------------------------
__global__ __launch_bounds__(256) void k_pre(
    const float* __restrict__ dist, const float* __restrict__ speed,
    const float* __restrict__ Wk, const float* __restrict__ Wv,
    int* __restrict__ Kout,
    int* __restrict__ candIdx, float* __restrict__ candDist,
    unsigned short* __restrict__ WkT, unsigned short* __restrict__ WvT) {
    int t = threadIdx.x;
    int bid = blockIdx.x;

    if (bid < 16) {
        __shared__ float sdist[CN];
        __shared__ unsigned long long red64[4];
        int b = bid;
        for (int i = t; i < CN; i += 256) sdist[i] = dist[b * CN + i];
        __syncthreads();
        for (int sel = 0; sel < KM1; sel++) {
            unsigned long long best = 0xFFFFFFFFFFFFFFFFull;
            for (int i = t; i < CN; i += 256) {
                unsigned long long key =
                    ((unsigned long long)__float_as_uint(sdist[i]) << 32) | (unsigned)i;
                best = best < key ? best : key;
            }
#pragma unroll
            for (int off = 32; off; off >>= 1) {
                unsigned long long o = __shfl_xor(best, off);
                best = best < o ? best : o;
            }
            if ((t & 63) == 0) red64[t >> 6] = best;
            __syncthreads();
            if (t == 0) {
                unsigned long long m0 = red64[0] < red64[1] ? red64[0] : red64[1];
                unsigned long long m1 = red64[2] < red64[3] ? red64[2] : red64[3];
                unsigned long long m = m0 < m1 ? m0 : m1;
                int idx = (int)(unsigned)(m & 0xFFFFFFFFu);
                candIdx[b * KM1 + sel]  = idx;
                candDist[b * KM1 + sel] = __uint_as_float((unsigned)(m >> 32));
                sdist[idx] = 3.4e38f;
            }
            __syncthreads();
        }
        return;
    }
    if (bid < 144) {
        __shared__ unsigned short tile[64][68];
        int b2 = bid - 16;
        int kt = b2 & 7, ct = (b2 >> 3) & 7, mat = b2 >> 6;
        const float* W = mat ? Wv : Wk;
        unsigned short* WT = mat ? WvT : WkT;
        int k0 = kt * 64, c0 = ct * 64;
#pragma unroll
        for (int p = 0; p < 4; p++) {
            int kr = p * 16 + (t >> 4);
            int cc = (t & 15) * 4;
            float4 v = *(const float4*)(W + (size_t)(k0 + kr) * CD + c0 + cc);
            *(us4*)&tile[kr][cc] = pack4(v);
        }
        __syncthreads();
#pragma unroll
        for (int p = 0; p < 4; p++) {
            int cr = p * 16 + (t >> 4);
            int kk = (t & 15) * 4;
            us4 o;
            o.x = tile[kk + 0][cr];
            o.y = tile[kk + 1][cr];
            o.z = tile[kk + 2][cr];
            o.w = tile[kk + 3][cr];
            *(us4*)(WT + (size_t)(c0 + cr) * CD + k0 + kk) = o;
        }
        return;
    }
    {
        __shared__ int red[256];
        int cnt = 0;
        for (int i = t; i < CB * CN; i += 256) cnt += (dist[i] < 20.0f) ? 1 : 0;
        red[t] = cnt;
        __syncthreads();
        for (int s = 128; s > 0; s >>= 1) {
            if (t < s) red[t] += red[t + s];
            __syncthreads();
        }
        if (t == 0) {
            float ss = 0.f;
            for (int i = 0; i < CB; i++) ss += speed[i];
            int K = 4;
            if (ss / (float)CB > 15.0f) K = (K + 1 > 6) ? 6 : K + 1;
            float density = (float)red[0] / (float)(CB * CN);
            if (density > 0.5f) K = (K + 1 > 6) ? 6 : K + 1;
            if (K > CN - 1) K = CN - 1;
            if (K < 0) K = 0;
            *Kout = K;
        }
    }
}

// ---------------------------------------------------------------------------
// Kernel MID: bid<128 -> Vc blocks (b,ny) writing bf16 Vc;
// 128..383 -> Y blocks (b,h,half) recomputing their 7x64 Kc slice locally.
// ---------------------------------------------------------------------------
__global__ __launch_bounds__(256) void k_mid(
    const float* __restrict__ X,
    const unsigned short* __restrict__ WkT, const float* __restrict__ bk,
    const unsigned short* __restrict__ WvT, const float* __restrict__ bv,
    const float* __restrict__ Wq, const float* __restrict__ bq,
    const float* __restrict__ Weq, const float* __restrict__ beq,
    const int* __restrict__ candIdx,
    unsigned short* __restrict__ VcB, float* __restrict__ S0,
    unsigned short* __restrict__ Y) {
    int t = threadIdx.x;
    int bid = blockIdx.x;
    __shared__ unsigned short sbuf[16][520];

    int b = (bid < 128) ? (bid >> 3) : ((bid - 128) >> 4);
    for (int i = t; i < 16 * 128; i += 256) {
        int m = i >> 7, c4 = i & 127;
        float4 xv = {0.f, 0.f, 0.f, 0.f};
        if (m < KM1)
            xv = *(const float4*)(X + (size_t)(b * CN + candIdx[b * KM1 + m]) * CD + c4 * 4);
        *(us4*)&sbuf[m][c4 * 4] = pack4(xv);
    }
    __syncthreads();

    int w = t >> 6, lane = t & 63, lr = lane & 15, kg = lane >> 4;

    if (bid < 128) {
        int ny = bid & 7;
        int c = ny * 64 + w * 16 + lr;
        const unsigned short* wtp = WvT + (size_t)c * CD + kg * 8;
        f32x4 acc = {0.f, 0.f, 0.f, 0.f};
#pragma unroll
        for (int s = 0; s < 16; s++) {
            bf8 bfr = *(const bf8*)(wtp + s * 32);
            bf8 a   = *(const bf8*)&sbuf[lr][s * 32 + kg * 8];
            acc = __builtin_amdgcn_mfma_f32_16x16x32_bf16(a, bfr, acc, 0, 0, 0);
        }
        float bv_ = bv[c];
#pragma unroll
        for (int q = 0; q < 4; q++) {
            int m = kg * 4 + q;
            if (m < KM1)
                VcB[(size_t)(b * KM1 + m) * CD + c] = f2bf(acc[q] + bv_);
        }
        return;
    }

    int rem = (bid - 128) & 15;
    int h = rem >> 1, half = rem & 1;
    __shared__ unsigned short sKc16[16][68];
    __shared__ float sKcf[KM1][64];

    {
        int c = h * 64 + w * 16 + lr;
        const unsigned short* wtp = WkT + (size_t)c * CD + kg * 8;
        f32x4 acc = {0.f, 0.f, 0.f, 0.f};
#pragma unroll
        for (int s = 0; s < 16; s++) {
            bf8 bfr = *(const bf8*)(wtp + s * 32);
            bf8 a   = *(const bf8*)&sbuf[lr][s * 32 + kg * 8];
            acc = __builtin_amdgcn_mfma_f32_16x16x32_bf16(a, bfr, acc, 0, 0, 0);
        }
        float bk_ = bk[c];
        int cl = w * 16 + lr;
#pragma unroll
        for (int q = 0; q < 4; q++) {
            int m = kg * 4 + q;
            float val = (m < KM1) ? (acc[q] + bk_) : 0.f;
            sKc16[m][cl] = f2bf(val);
            if (m < KM1) sKcf[m][cl] = val;
        }
    }
    __syncthreads();

    if (half == 0 && t < 14) {
        int mat = t / 7, m = t % 7;
        const float* bias = mat ? beq : bq;
        float s = 0.f;
        for (int c = 0; c < 64; c++) s = fmaf(bias[h * 64 + c], sKcf[m][c], s);
        S0[((b * 2 + mat) * KM1 + m) * 8 + h] = s;
    }

    bf8 a0 = *(const bf8*)&sKc16[lr][kg * 8];
    bf8 a1 = *(const bf8*)&sKc16[lr][32 + kg * 8];
    unsigned short* Y2b = Y + (size_t)b * 64 * 112 * 8;
#pragma unroll
    for (int mat = 0; mat < 2; mat++) {
        const float* W = mat ? Weq : Wq;
#pragma unroll
        for (int nt = 0; nt < 4; nt++) {
            int n0 = (half * 16 + w * 4 + nt) * 16;
            const float* wp = W + (size_t)(n0 + lr) * CD + h * 64 + kg * 8;
            float4 f0 = *(const float4*)(wp);
            float4 f1 = *(const float4*)(wp + 4);
            float4 f2 = *(const float4*)(wp + 32);
            float4 f3 = *(const float4*)(wp + 36);
            f32x4 acc = {0.f, 0.f, 0.f, 0.f};
            acc = __builtin_amdgcn_mfma_f32_16x16x32_bf16(a0, pack8(f0, f1), acc, 0, 0, 0);
            acc = __builtin_amdgcn_mfma_f32_16x16x32_bf16(a1, pack8(f2, f3), acc, 0, 0, 0);
            int k_out = n0 + lr;
            int k8 = k_out >> 3, krem = k_out & 7;
#pragma unroll
            for (int q = 0; q < 4; q++) {
                int m = kg * 4 + q;
                if (m < KM1) {
                    int n = mat * 56 + m * 8 + h;
                    Y2b[((size_t)k8 * 112 + n) * 8 + krem] = f2bf(acc[q]);
                }
            }
        }
    }
}

// ---------------------------------------------------------------------------
// Kernel attn: 512 threads/block, 32 rows/block, grid 512.
//   Phase A: stage X tile row-major bf16 in LDS (coalesced) + V + metadata.
//   Waves 0-3: score MFMA (B1, A-frags from LDS).  Waves 4-7: bias MLP (B2).
//   Fused blend+softmax+W7 (phase D); PV fixed-7 loop + residual(LDS) + LN.
// ---------------------------------------------------------------------------
__global__ __launch_bounds__(512) void k_attn(
    const float* __restrict__ X, const float* __restrict__ dist,
    const float* __restrict__ mask,
    const float* __restrict__ Wd1, const float* __restrict__ bd1,
    const float* __restrict__ Wd2, const float* __restrict__ bd2,
    const float* __restrict__ lng, const float* __restrict__ lnb,
    const int* __restrict__ Kp, const int* __restrict__ candIdx,
    const float* __restrict__ candDist,
    const unsigned short* __restrict__ VcB, const float* __restrict__ S0,
    const unsigned short* __restrict__ Y,
    float* __restrict__ out) {

    __shared__ unsigned short sX[RB][520];     // X tile bf16, row-major
    __shared__ float sS[RB][116];
    __shared__ unsigned short sVc[KM1][520];
    __shared__ float sW7[RB][8][8];
    __shared__ float sBias[RB][6][2][8];
    __shared__ int   snbr[RB][6];
    __shared__ float skd[RB][6];
    __shared__ float srd[RB];
    __shared__ float sE[RB];
    __shared__ float sS0[112];

    int t = threadIdx.x;
    int b = blockIdx.x >> 5, rblk = blockIdx.x & 31;
    int row0 = b * CN + rblk * RB;
    int K = *Kp;

    // ---- phase A: stage X tile (bf16) + V rows + metadata
    for (int idx = t; idx < RB * 128; idx += 512) {
        int r = idx >> 7, c4 = idx & 127;
        float4 xv = *(const float4*)(X + (size_t)(row0 + r) * CD + c4 * 4);
        *(us4*)&sX[r][c4 * 4] = pack4(xv);
    }
    for (int idx = t; idx < KM1 * 128; idx += 512) {
        int m = idx >> 7, c4 = idx & 127;
        *(us4*)&sVc[m][c4 * 4] =
            *(const us4*)(VcB + (size_t)(b * KM1 + m) * CD + c4 * 4);
    }
    if (t < 112) sS0[t] = S0[b * 112 + t];
    if (t < RB) {
        int i = rblk * RB + t;
        sE[t]  = mask[b * CN + i];
        srd[t] = dist[b * CN + i];
        int cnt = 0;
        for (int m = 0; m <= K && cnt < K; m++) {
            int c = candIdx[b * KM1 + m];
            if (c != i) { snbr[t][cnt] = m; skd[t][cnt] = candDist[b * KM1 + m]; cnt++; }
        }
    }
    __syncthreads();

    int w = t >> 6;
    if (w < 4) {
        // ---- phase B1 (waves 0-3): score MFMA  S[r][n] = X_r . Y_n
        int lane = t & 63, lr = lane & 15, kg = lane >> 4;
        f32x4 acc00 = {0.f, 0.f, 0.f, 0.f}, acc10 = acc00, acc01 = acc00, acc11 = acc00;
        bool has2 = (w < 3);
        const unsigned short* ypk = Y + ((size_t)b * 64 * 112 + (size_t)kg * 112 + (w * 16 + lr)) * 8;
#pragma unroll
        for (int s = 0; s < 16; s++) {
            int k0 = s * 32 + kg * 8;
            bf8 a0 = *(const bf8*)&sX[lr][k0];
            bf8 a1 = *(const bf8*)&sX[16 + lr][k0];
            const unsigned short* ys = ypk + (size_t)s * 4 * 112 * 8;
            bf8 b0 = *(const bf8*)ys;
            acc00 = __builtin_amdgcn_mfma_f32_16x16x32_bf16(a0, b0, acc00, 0, 0, 0);
            acc10 = __builtin_amdgcn_mfma_f32_16x16x32_bf16(a1, b0, acc10, 0, 0, 0);
            if (has2) {
                bf8 b1 = *(const bf8*)(ys + 512);
                acc01 = __builtin_amdgcn_mfma_f32_16x16x32_bf16(a0, b1, acc01, 0, 0, 0);
                acc11 = __builtin_amdgcn_mfma_f32_16x16x32_bf16(a1, b1, acc11, 0, 0, 0);
            }
        }
        int n0 = w * 16 + lr;
#pragma unroll
        for (int q = 0; q < 4; q++) {
            sS[kg * 4 + q][n0]      = acc00[q];
            sS[16 + kg * 4 + q][n0] = acc10[q];
        }
        if (has2) {
            int n1 = (w + 4) * 16 + lr;
#pragma unroll
            for (int q = 0; q < 4; q++) {
                sS[kg * 4 + q][n1]      = acc01[q];
                sS[16 + kg * 4 + q][n1] = acc11[q];
            }
        }
    } else {
        int tot2 = RB * K * 2;
        for (int task = t - 256; task < tot2; task += 256) {
            int half = task & 1;
            int pid = task >> 1;
            int r = pid / K, k = pid - r * K;
            int j0 = half * 64;
            float qd = srd[r], kd = skd[r][k];
            float bacc[8];
#pragma unroll
            for (int h = 0; h < 8; h++) bacc[h] = 0.f;
            for (int j = j0; j < j0 + 64; j++) {
                float hid = fmaf(qd, Wd1[j], fmaf(kd, Wd1[128 + j], bd1[j]));
                hid = fmaxf(hid, 0.f);
                float4 wa = *(const float4*)(Wd2 + j * 8);
                float4 wb = *(const float4*)(Wd2 + j * 8 + 4);
                bacc[0] = fmaf(hid, wa.x, bacc[0]);
                bacc[1] = fmaf(hid, wa.y, bacc[1]);
                bacc[2] = fmaf(hid, wa.z, bacc[2]);
                bacc[3] = fmaf(hid, wa.w, bacc[3]);
                bacc[4] = fmaf(hid, wb.x, bacc[4]);
                bacc[5] = fmaf(hid, wb.y, bacc[5]);
                bacc[6] = fmaf(hid, wb.z, bacc[6]);
                bacc[7] = fmaf(hid, wb.w, bacc[7]);
            }
#pragma unroll
            for (int h = 0; h < 8; h++) sBias[r][k][half][h] = bacc[h];
        }
    }
    __syncthreads();

    // ---- phase D (fused blend + softmax + W7, all in registers)
    if (t < RB * 8) {
        int r = t >> 3, h = t & 7;
        float e = sE[r];
        float wv[6];
#pragma unroll
        for (int k = 0; k < 6; k++) {
            if (k < K) {
                int m = snbr[r][k];
                float scq = sS[r][m * 8 + h]      + sS0[m * 8 + h];
                float sce = sS[r][56 + m * 8 + h] + sS0[56 + m * 8 + h];
                float sc = (1.f - e) * scq + e * sce;
                float bias = sBias[r][k][0][h] + sBias[r][k][1][h] + bd2[h];
                wv[k] = sc * 0.125f * bias;
            } else {
                wv[k] = -3.4e38f;
            }
        }
        float mx = -3.4e38f;
#pragma unroll
        for (int k = 0; k < 6; k++) mx = fmaxf(mx, wv[k]);
        float sum = 0.f;
#pragma unroll
        for (int k = 0; k < 6; k++) {
            wv[k] = __expf(wv[k] - mx);
            sum += wv[k];
        }
        float inv = 1.f / sum;
#pragma unroll
        for (int m = 0; m < KM1; m++) {
            float acc = 0.f;
#pragma unroll
            for (int k = 0; k < 6; k++) {
                bool use = (k < K) && (snbr[r][k] == m);
                acc += use ? wv[k] * inv : 0.f;
            }
            sW7[r][h][m] = acc;
        }
    }
    __syncthreads();

    // ---- phase E: PV (fixed 7-slot loop) + residual(LDS bf16) + LN
    {
        int r = t >> 4, tr = t & 15;
        float4 vals[8];
        float sum = 0.f, sq = 0.f;
#pragma unroll
        for (int j = 0; j < 8; j++) {
            int d = tr * 4 + j * 64;    // head h = j
            float ax = 0.f, ay = 0.f, az = 0.f, aw = 0.f;
#pragma unroll
            for (int m = 0; m < KM1; m++) {
                float wgt = sW7[r][j][m];
                us4 vv = *(const us4*)&sVc[m][d];
                ax = fmaf(wgt, bf2f(vv.x), ax);
                ay = fmaf(wgt, bf2f(vv.y), ay);
                az = fmaf(wgt, bf2f(vv.z), az);
                aw = fmaf(wgt, bf2f(vv.w), aw);
            }
            us4 xb = *(const us4*)&sX[r][d];
            float4 v;
            v.x = bf2f(xb.x) + ax; v.y = bf2f(xb.y) + ay;
            v.z = bf2f(xb.z) + az; v.w = bf2f(xb.w) + aw;
            vals[j] = v;
            sum += v.x + v.y + v.z + v.w;
            sq = fmaf(v.x, v.x, sq); sq = fmaf(v.y, v.y, sq);
            sq = fmaf(v.z, v.z, sq); sq = fmaf(v.w, v.w, sq);
        }
        sum += __shfl_xor(sum, 1, 16); sq += __shfl_xor(sq, 1, 16);
        sum += __shfl_xor(sum, 2, 16); sq += __shfl_xor(sq, 2, 16);
        sum += __shfl_xor(sum, 4, 16); sq += __shfl_xor(sq, 4, 16);
        sum += __shfl_xor(sum, 8, 16); sq += __shfl_xor(sq, 8, 16);
        float mu  = sum * (1.f / 512.f);
        float var = sq * (1.f / 512.f) - mu * mu;
        float inv = rsqrtf(var + 1e-5f);
        int gr = row0 + r;
        float* orow = out + (size_t)gr * CD;
#pragma unroll
        for (int j = 0; j < 8; j++) {
            int d = tr * 4 + j * 64;
            float4 g  = *(const float4*)(lng + d);
            float4 bb = *(const float4*)(lnb + d);
            float4 v = vals[j];
            float4 o;
            o.x = (v.x - mu) * inv * g.x + bb.x;
            o.y = (v.y - mu) * inv * g.y + bb.y;
            o.z = (v.z - mu) * inv * g.z + bb.z;
            o.w = (v.w - mu) * inv * g.w + bb.w;
            *(float4*)(orow + d) = o;
        }
    }
}

// ---------------------------------------------------------------------------
extern "C" void kernel_launch(void* const* d_in, const int* in_sizes, int n_in,
                              void* d_out, int out_size, void* d_ws, size_t ws_size,
                              hipStream_t stream) {
    (void)in_sizes; (void)n_in; (void)out_size; (void)ws_size;
    const float* X     = (const float*)d_in[0];
    const float* dist  = (const float*)d_in[1];
    const float* mask  = (const float*)d_in[2];
    const float* speed = (const float*)d_in[3];
    const float* Wq    = (const float*)d_in[4];
    const float* bq    = (const float*)d_in[5];
    const float* Wk    = (const float*)d_in[6];
    const float* bk    = (const float*)d_in[7];
    const float* Wv    = (const float*)d_in[8];
    const float* bv    = (const float*)d_in[9];
    const float* Weq   = (const float*)d_in[10];
    const float* beq   = (const float*)d_in[11];
    const float* Wd1   = (const float*)d_in[16];
    const float* bd1   = (const float*)d_in[17];
    const float* Wd2   = (const float*)d_in[18];
    const float* bd2   = (const float*)d_in[19];
    const float* lng   = (const float*)d_in[20];
    const float* lnb   = (const float*)d_in[21];
    float* out = (float*)d_out;

    char* ws = (char*)d_ws;
    int*   Kp       = (int*)(ws);
    int*   candIdx  = (int*)(ws + 256);
    float* candDist = (float*)(ws + 1024);
    float* S0       = (float*)(ws + 2048);                 // 7168 B
    unsigned short* VcB = (unsigned short*)(ws + 245760);  // 114688 B (bf16)
    unsigned short* Y   = (unsigned short*)(ws + 475136);  // 1835008 B (Y2 layout)
    unsigned short* WkT = (unsigned short*)(ws + 2310144); // 524288 B
    unsigned short* WvT = (unsigned short*)(ws + 2834432); // 524288 B

    k_pre<<<145, 256, 0, stream>>>(dist, speed, Wk, Wv, Kp, candIdx, candDist, WkT, WvT);
    k_mid<<<384, 256, 0, stream>>>(X, WkT, bk, WvT, bv, Wq, bq, Weq, beq,
                                   candIdx, VcB, S0, Y);
    k_attn<<<CB * (CN / RB), 512, 0, stream>>>(X, dist, mask, Wd1, bd1, Wd2, bd2, lng, lnb,
                                               Kp, candIdx, candDist, VcB, S0, Y, out);
}

// Round 18
// 74.125 us; speedup vs baseline: 1.0911x; 1.0911x over previous
//
#include <hip/hip_runtime.h>
#include <math.h>

constexpr int CB  = 16;
constexpr int CN  = 1024;
constexpr int CD  = 512;
constexpr int KM1 = 7;      // K_MAX + 1 candidate slots per batch
constexpr int RB  = 32;     // rows per k_attn block

typedef __attribute__((ext_vector_type(8))) short bf8;
typedef __attribute__((ext_vector_type(4))) float f32x4;
typedef __attribute__((ext_vector_type(4))) unsigned short us4;

__device__ inline float bf2f(unsigned short u) {
    union { unsigned int i; float f; } v; v.i = ((unsigned)u) << 16; return v.f;
}
__device__ inline unsigned short f2bf(float f) {
    union { unsigned int i; float f; } v; v.f = f;
    unsigned r = v.i + 0x7FFFu + ((v.i >> 16) & 1u);
    return (unsigned short)(r >> 16);
}
// packed f32->bf16 (RNE) via HW instruction
__device__ inline unsigned int cvtpk(float lo, float hi) {
    unsigned int r;
    asm("v_cvt_pk_bf16_f32 %0, %1, %2" : "=v"(r) : "v"(lo), "v"(hi));
    return r;
}
__device__ inline bf8 pack8(float4 x, float4 y) {
    union { bf8 v; unsigned int u[4]; } r;
    r.u[0] = cvtpk(x.x, x.y); r.u[1] = cvtpk(x.z, x.w);
    r.u[2] = cvtpk(y.x, y.y); r.u[3] = cvtpk(y.z, y.w);
    return r.v;
}
__device__ inline us4 pack4(float4 x) {
    union { us4 v; unsigned int u[2]; } r;
    r.u[0] = cvtpk(x.x, x.y); r.u[1] = cvtpk(x.z, x.w);
    return r.v;
}

// ---------------------------------------------------------------------------
// Kernel PRE: blocks 0..15 top-7 (wave-parallel packed-min) |
// 16..143 transW | 144 computeK.
// ---------------------------------------------------------------------------
__global__ __launch_bounds__(256) void k_pre(
    const float* __restrict__ dist, const float* __restrict__ speed,
    const float* __restrict__ Wk, const float* __restrict__ Wv,
    int* __restrict__ Kout,
    int* __restrict__ candIdx, float* __restrict__ candDist,
    unsigned short* __restrict__ WkT, unsigned short* __restrict__ WvT) {
    int t = threadIdx.x;
    int bid = blockIdx.x;

    if (bid < 16) {
        __shared__ float sdist[CN];
        __shared__ unsigned long long red64[4];
        int b = bid;
        for (int i = t; i < CN; i += 256) sdist[i] = dist[b * CN + i];
        __syncthreads();
        for (int sel = 0; sel < KM1; sel++) {
            unsigned long long best = 0xFFFFFFFFFFFFFFFFull;
            for (int i = t; i < CN; i += 256) {
                unsigned long long key =
                    ((unsigned long long)__float_as_uint(sdist[i]) << 32) | (unsigned)i;
                best = best < key ? best : key;
            }
#pragma unroll
            for (int off = 32; off; off >>= 1) {
                unsigned long long o = __shfl_xor(best, off);
                best = best < o ? best : o;
            }
            if ((t & 63) == 0) red64[t >> 6] = best;
            __syncthreads();
            if (t == 0) {
                unsigned long long m0 = red64[0] < red64[1] ? red64[0] : red64[1];
                unsigned long long m1 = red64[2] < red64[3] ? red64[2] : red64[3];
                unsigned long long m = m0 < m1 ? m0 : m1;
                int idx = (int)(unsigned)(m & 0xFFFFFFFFu);
                candIdx[b * KM1 + sel]  = idx;
                candDist[b * KM1 + sel] = __uint_as_float((unsigned)(m >> 32));
                sdist[idx] = 3.4e38f;
            }
            __syncthreads();
        }
        return;
    }
    if (bid < 144) {
        __shared__ unsigned short tile[64][68];
        int b2 = bid - 16;
        int kt = b2 & 7, ct = (b2 >> 3) & 7, mat = b2 >> 6;
        const float* W = mat ? Wv : Wk;
        unsigned short* WT = mat ? WvT : WkT;
        int k0 = kt * 64, c0 = ct * 64;
#pragma unroll
        for (int p = 0; p < 4; p++) {
            int kr = p * 16 + (t >> 4);
            int cc = (t & 15) * 4;
            float4 v = *(const float4*)(W + (size_t)(k0 + kr) * CD + c0 + cc);
            *(us4*)&tile[kr][cc] = pack4(v);
        }
        __syncthreads();
#pragma unroll
        for (int p = 0; p < 4; p++) {
            int cr = p * 16 + (t >> 4);
            int kk = (t & 15) * 4;
            us4 o;
            o.x = tile[kk + 0][cr];
            o.y = tile[kk + 1][cr];
            o.z = tile[kk + 2][cr];
            o.w = tile[kk + 3][cr];
            *(us4*)(WT + (size_t)(c0 + cr) * CD + k0 + kk) = o;
        }
        return;
    }
    {
        __shared__ int red[256];
        int cnt = 0;
        for (int i = t; i < CB * CN; i += 256) cnt += (dist[i] < 20.0f) ? 1 : 0;
        red[t] = cnt;
        __syncthreads();
        for (int s = 128; s > 0; s >>= 1) {
            if (t < s) red[t] += red[t + s];
            __syncthreads();
        }
        if (t == 0) {
            float ss = 0.f;
            for (int i = 0; i < CB; i++) ss += speed[i];
            int K = 4;
            if (ss / (float)CB > 15.0f) K = (K + 1 > 6) ? 6 : K + 1;
            float density = (float)red[0] / (float)(CB * CN);
            if (density > 0.5f) K = (K + 1 > 6) ? 6 : K + 1;
            if (K > CN - 1) K = CN - 1;
            if (K < 0) K = 0;
            *Kout = K;
        }
    }
}

// ---------------------------------------------------------------------------
// Kernel MID: bid<128 -> Vc blocks (b,ny) writing bf16 Vc;
// 128..639 -> Y blocks (b,h,half,mat), each recomputing its 7x64 Kc slice
// locally and emitting 4 n-tiles of one matrix (2x the TLP of the old
// 8-tile blocks); bid>=640 -> X2 fragment-major repack.
// ---------------------------------------------------------------------------
__global__ __launch_bounds__(256) void k_mid(
    const float* __restrict__ X,
    const unsigned short* __restrict__ WkT, const float* __restrict__ bk,
    const unsigned short* __restrict__ WvT, const float* __restrict__ bv,
    const float* __restrict__ Wq, const float* __restrict__ bq,
    const float* __restrict__ Weq, const float* __restrict__ beq,
    const int* __restrict__ candIdx,
    unsigned short* __restrict__ VcB, float* __restrict__ S0,
    unsigned short* __restrict__ Y,
    unsigned short* __restrict__ X2) {
    int t = threadIdx.x;
    int bid = blockIdx.x;
    __shared__ unsigned short sbuf[RB][520];   // repack: 32 rows; Vc/Y: rows 0..15

    if (bid >= 640) {
        // ---- X2 repack: one block per 32-row tile
        int tileId = bid - 640;                  // 0..511 == k_attn blockIdx.x
        int b = tileId >> 5, rblk = tileId & 31;
        int row0 = b * CN + rblk * RB;
        for (int idx = t; idx < RB * 128; idx += 256) {
            int r = idx >> 7, c4 = idx & 127;
            float4 xv = *(const float4*)(X + (size_t)(row0 + r) * CD + c4 * 4);
            *(us4*)&sbuf[r][c4 * 4] = pack4(xv);
        }
        __syncthreads();
        unsigned short* dst = X2 + (size_t)tileId * 16384;
#pragma unroll
        for (int it = 0; it < 8; it++) {
            int unit = t + it * 256;            // unit = s*128 + kg*32 + r
            int r = unit & 31, kg = (unit >> 5) & 3, s = unit >> 7;
            const unsigned short* src = &sbuf[r][s * 32 + kg * 8];
            us4 lo = *(const us4*)src;
            us4 hi = *(const us4*)(src + 4);
            *(us4*)(dst + (size_t)unit * 8)     = lo;
            *(us4*)(dst + (size_t)unit * 8 + 4) = hi;
        }
        return;
    }

    int b = (bid < 128) ? (bid >> 3) : ((bid - 128) >> 5);
    for (int i = t; i < 16 * 128; i += 256) {
        int m = i >> 7, c4 = i & 127;
        float4 xv = {0.f, 0.f, 0.f, 0.f};
        if (m < KM1)
            xv = *(const float4*)(X + (size_t)(b * CN + candIdx[b * KM1 + m]) * CD + c4 * 4);
        *(us4*)&sbuf[m][c4 * 4] = pack4(xv);
    }
    __syncthreads();

    int w = t >> 6, lane = t & 63, lr = lane & 15, kg = lane >> 4;

    if (bid < 128) {
        int ny = bid & 7;
        int c = ny * 64 + w * 16 + lr;
        const unsigned short* wtp = WvT + (size_t)c * CD + kg * 8;
        f32x4 acc = {0.f, 0.f, 0.f, 0.f};
#pragma unroll
        for (int s = 0; s < 16; s++) {
            bf8 bfr = *(const bf8*)(wtp + s * 32);
            bf8 a   = *(const bf8*)&sbuf[lr][s * 32 + kg * 8];
            acc = __builtin_amdgcn_mfma_f32_16x16x32_bf16(a, bfr, acc, 0, 0, 0);
        }
        float bv_ = bv[c];
#pragma unroll
        for (int q = 0; q < 4; q++) {
            int m = kg * 4 + q;
            if (m < KM1)
                VcB[(size_t)(b * KM1 + m) * CD + c] = f2bf(acc[q] + bv_);
        }
        return;
    }

    // ---- Y block: (b, h, half, mat)
    int rem = (bid - 128) & 31;
    int h = rem >> 2, half = (rem >> 1) & 1, mat = rem & 1;
    __shared__ unsigned short sKc16[16][68];
    __shared__ float sKcf[KM1][64];

    {
        int c = h * 64 + w * 16 + lr;
        const unsigned short* wtp = WkT + (size_t)c * CD + kg * 8;
        f32x4 acc = {0.f, 0.f, 0.f, 0.f};
#pragma unroll
        for (int s = 0; s < 16; s++) {
            bf8 bfr = *(const bf8*)(wtp + s * 32);
            bf8 a   = *(const bf8*)&sbuf[lr][s * 32 + kg * 8];
            acc = __builtin_amdgcn_mfma_f32_16x16x32_bf16(a, bfr, acc, 0, 0, 0);
        }
        float bk_ = bk[c];
        int cl = w * 16 + lr;
#pragma unroll
        for (int q = 0; q < 4; q++) {
            int m = kg * 4 + q;
            float val = (m < KM1) ? (acc[q] + bk_) : 0.f;
            sKc16[m][cl] = f2bf(val);
            if (m < KM1) sKcf[m][cl] = val;
        }
    }
    __syncthreads();

    if (half == 0 && t < KM1) {
        int m = t;
        const float* bias = mat ? beq : bq;
        float s = 0.f;
        for (int c = 0; c < 64; c++) s = fmaf(bias[h * 64 + c], sKcf[m][c], s);
        S0[((b * 2 + mat) * KM1 + m) * 8 + h] = s;
    }

    bf8 a0 = *(const bf8*)&sKc16[lr][kg * 8];
    bf8 a1 = *(const bf8*)&sKc16[lr][32 + kg * 8];
    unsigned short* Y2b = Y + (size_t)b * 64 * 112 * 8;
    const float* W = mat ? Weq : Wq;
#pragma unroll
    for (int nt = 0; nt < 4; nt++) {
        int n0 = (half * 16 + w * 4 + nt) * 16;
        const float* wp = W + (size_t)(n0 + lr) * CD + h * 64 + kg * 8;
        float4 f0 = *(const float4*)(wp);
        float4 f1 = *(const float4*)(wp + 4);
        float4 f2 = *(const float4*)(wp + 32);
        float4 f3 = *(const float4*)(wp + 36);
        f32x4 acc = {0.f, 0.f, 0.f, 0.f};
        acc = __builtin_amdgcn_mfma_f32_16x16x32_bf16(a0, pack8(f0, f1), acc, 0, 0, 0);
        acc = __builtin_amdgcn_mfma_f32_16x16x32_bf16(a1, pack8(f2, f3), acc, 0, 0, 0);
        int k_out = n0 + lr;
        int k8 = k_out >> 3, krem = k_out & 7;
#pragma unroll
        for (int q = 0; q < 4; q++) {
            int m = kg * 4 + q;
            if (m < KM1) {
                int n = mat * 56 + m * 8 + h;
                Y2b[((size_t)k8 * 112 + n) * 8 + krem] = f2bf(acc[q]);
            }
        }
    }
}

// ---------------------------------------------------------------------------
// Kernel attn: 512 threads/block, 32 rows/block, grid 512.
//   Waves 0-3: score MFMA (B1, A-frags from X2).  Waves 4-7: bias MLP (B2).
//   Fused blend+softmax+W7 in registers (phase D); PV fixed-7 loop + LN.
// ---------------------------------------------------------------------------
__global__ __launch_bounds__(512) void k_attn(
    const float* __restrict__ X, const float* __restrict__ dist,
    const float* __restrict__ mask,
    const float* __restrict__ Wd1, const float* __restrict__ bd1,
    const float* __restrict__ Wd2, const float* __restrict__ bd2,
    const float* __restrict__ lng, const float* __restrict__ lnb,
    const int* __restrict__ Kp, const int* __restrict__ candIdx,
    const float* __restrict__ candDist,
    const unsigned short* __restrict__ VcB, const float* __restrict__ S0,
    const unsigned short* __restrict__ Y,
    const unsigned short* __restrict__ X2, int useX2,
    float* __restrict__ out) {

    __shared__ float sS[RB][116];
    __shared__ unsigned short sVc[KM1][520];
    __shared__ float sW7[RB][8][8];
    __shared__ float sBias[RB][6][2][8];
    __shared__ int   snbr[RB][6];
    __shared__ float skd[RB][6];
    __shared__ float srd[RB];
    __shared__ float sE[RB];
    __shared__ float sS0[112];

    int t = threadIdx.x;
    int b = blockIdx.x >> 5, rblk = blockIdx.x & 31;
    int row0 = b * CN + rblk * RB;
    int K = *Kp;

    for (int idx = t; idx < KM1 * 128; idx += 512) {
        int m = idx >> 7, c4 = idx & 127;
        *(us4*)&sVc[m][c4 * 4] =
            *(const us4*)(VcB + (size_t)(b * KM1 + m) * CD + c4 * 4);
    }
    if (t < 112) sS0[t] = S0[b * 112 + t];
    if (t < RB) {
        int i = rblk * RB + t;
        sE[t]  = mask[b * CN + i];
        srd[t] = dist[b * CN + i];
        int cnt = 0;
        for (int m = 0; m <= K && cnt < K; m++) {
            int c = candIdx[b * KM1 + m];
            if (c != i) { snbr[t][cnt] = m; skd[t][cnt] = candDist[b * KM1 + m]; cnt++; }
        }
    }
    __syncthreads();

    int w = t >> 6;
    if (w < 4) {
        int lane = t & 63, lr = lane & 15, kg = lane >> 4;
        f32x4 acc00 = {0.f, 0.f, 0.f, 0.f}, acc10 = acc00, acc01 = acc00, acc11 = acc00;
        bool has2 = (w < 3);
        const unsigned short* ypk = Y + ((size_t)b * 64 * 112 + (size_t)kg * 112 + (w * 16 + lr)) * 8;
        if (useX2) {
            const unsigned short* x2s = X2 + (size_t)blockIdx.x * 16384 + kg * 256 + lr * 8;
#pragma unroll
            for (int s = 0; s < 16; s++) {
                const unsigned short* xp = x2s + s * 1024;
                bf8 a0 = *(const bf8*)xp;
                bf8 a1 = *(const bf8*)(xp + 128);
                const unsigned short* ys = ypk + (size_t)s * 4 * 112 * 8;
                bf8 b0 = *(const bf8*)ys;
                acc00 = __builtin_amdgcn_mfma_f32_16x16x32_bf16(a0, b0, acc00, 0, 0, 0);
                acc10 = __builtin_amdgcn_mfma_f32_16x16x32_bf16(a1, b0, acc10, 0, 0, 0);
                if (has2) {
                    bf8 b1 = *(const bf8*)(ys + 512);
                    acc01 = __builtin_amdgcn_mfma_f32_16x16x32_bf16(a0, b1, acc01, 0, 0, 0);
                    acc11 = __builtin_amdgcn_mfma_f32_16x16x32_bf16(a1, b1, acc11, 0, 0, 0);
                }
            }
        } else {
            const float* x0 = X + (size_t)(row0 + lr) * CD + kg * 8;
            const float* x1 = X + (size_t)(row0 + 16 + lr) * CD + kg * 8;
#pragma unroll
            for (int s = 0; s < 16; s++) {
                int k0 = s * 32;
                float4 xa0 = *(const float4*)(x0 + k0);
                float4 xb0 = *(const float4*)(x0 + k0 + 4);
                float4 xa1 = *(const float4*)(x1 + k0);
                float4 xb1 = *(const float4*)(x1 + k0 + 4);
                bf8 a0 = pack8(xa0, xb0);
                bf8 a1 = pack8(xa1, xb1);
                const unsigned short* ys = ypk + (size_t)s * 4 * 112 * 8;
                bf8 b0 = *(const bf8*)ys;
                acc00 = __builtin_amdgcn_mfma_f32_16x16x32_bf16(a0, b0, acc00, 0, 0, 0);
                acc10 = __builtin_amdgcn_mfma_f32_16x16x32_bf16(a1, b0, acc10, 0, 0, 0);
                if (has2) {
                    bf8 b1 = *(const bf8*)(ys + 512);
                    acc01 = __builtin_amdgcn_mfma_f32_16x16x32_bf16(a0, b1, acc01, 0, 0, 0);
                    acc11 = __builtin_amdgcn_mfma_f32_16x16x32_bf16(a1, b1, acc11, 0, 0, 0);
                }
            }
        }
        int n0 = w * 16 + lr;
#pragma unroll
        for (int q = 0; q < 4; q++) {
            sS[kg * 4 + q][n0]      = acc00[q];
            sS[16 + kg * 4 + q][n0] = acc10[q];
        }
        if (has2) {
            int n1 = (w + 4) * 16 + lr;
#pragma unroll
            for (int q = 0; q < 4; q++) {
                sS[kg * 4 + q][n1]      = acc01[q];
                sS[16 + kg * 4 + q][n1] = acc11[q];
            }
        }
    } else {
        int tot2 = RB * K * 2;
        for (int task = t - 256; task < tot2; task += 256) {
            int half = task & 1;
            int pid = task >> 1;
            int r = pid / K, k = pid - r * K;
            int j0 = half * 64;
            float qd = srd[r], kd = skd[r][k];
            float bacc[8];
#pragma unroll
            for (int h = 0; h < 8; h++) bacc[h] = 0.f;
            for (int j = j0; j < j0 + 64; j++) {
                float hid = fmaf(qd, Wd1[j], fmaf(kd, Wd1[128 + j], bd1[j]));
                hid = fmaxf(hid, 0.f);
                float4 wa = *(const float4*)(Wd2 + j * 8);
                float4 wb = *(const float4*)(Wd2 + j * 8 + 4);
                bacc[0] = fmaf(hid, wa.x, bacc[0]);
                bacc[1] = fmaf(hid, wa.y, bacc[1]);
                bacc[2] = fmaf(hid, wa.z, bacc[2]);
                bacc[3] = fmaf(hid, wa.w, bacc[3]);
                bacc[4] = fmaf(hid, wb.x, bacc[4]);
                bacc[5] = fmaf(hid, wb.y, bacc[5]);
                bacc[6] = fmaf(hid, wb.z, bacc[6]);
                bacc[7] = fmaf(hid, wb.w, bacc[7]);
            }
#pragma unroll
            for (int h = 0; h < 8; h++) sBias[r][k][half][h] = bacc[h];
        }
    }
    __syncthreads();

    // ---- phase D (fused blend + softmax + W7, all in registers)
    if (t < RB * 8) {
        int r = t >> 3, h = t & 7;
        float e = sE[r];
        float wv[6];
#pragma unroll
        for (int k = 0; k < 6; k++) {
            if (k < K) {
                int m = snbr[r][k];
                float scq = sS[r][m * 8 + h]      + sS0[m * 8 + h];
                float sce = sS[r][56 + m * 8 + h] + sS0[56 + m * 8 + h];
                float sc = (1.f - e) * scq + e * sce;
                float bias = sBias[r][k][0][h] + sBias[r][k][1][h] + bd2[h];
                wv[k] = sc * 0.125f * bias;
            } else {
                wv[k] = -3.4e38f;
            }
        }
        float mx = -3.4e38f;
#pragma unroll
        for (int k = 0; k < 6; k++) mx = fmaxf(mx, wv[k]);
        float sum = 0.f;
#pragma unroll
        for (int k = 0; k < 6; k++) {
            wv[k] = __expf(wv[k] - mx);
            sum += wv[k];
        }
        float inv = 1.f / sum;
#pragma unroll
        for (int m = 0; m < KM1; m++) {
            float acc = 0.f;
#pragma unroll
            for (int k = 0; k < 6; k++) {
                bool use = (k < K) && (snbr[r][k] == m);
                acc += use ? wv[k] * inv : 0.f;
            }
            sW7[r][h][m] = acc;
        }
    }
    __syncthreads();

    // ---- phase E: PV (fixed 7-slot loop) + residual + LN (16 thr/row, h=j)
    {
        int r = t >> 4, tr = t & 15;
        const float* xrow = X + (size_t)(row0 + r) * CD;
        float4 vals[8];
        float sum = 0.f, sq = 0.f;
#pragma unroll
        for (int j = 0; j < 8; j++) {
            int d = tr * 4 + j * 64;    // head h = j
            float ax = 0.f, ay = 0.f, az = 0.f, aw = 0.f;
#pragma unroll
            for (int m = 0; m < KM1; m++) {
                float wgt = sW7[r][j][m];
                us4 vv = *(const us4*)&sVc[m][d];
                ax = fmaf(wgt, bf2f(vv.x), ax);
                ay = fmaf(wgt, bf2f(vv.y), ay);
                az = fmaf(wgt, bf2f(vv.z), az);
                aw = fmaf(wgt, bf2f(vv.w), aw);
            }
            float4 xv = *(const float4*)(xrow + d);
            float4 v;
            v.x = xv.x + ax; v.y = xv.y + ay; v.z = xv.z + az; v.w = xv.w + aw;
            vals[j] = v;
            sum += v.x + v.y + v.z + v.w;
            sq = fmaf(v.x, v.x, sq); sq = fmaf(v.y, v.y, sq);
            sq = fmaf(v.z, v.z, sq); sq = fmaf(v.w, v.w, sq);
        }
        sum += __shfl_xor(sum, 1, 16); sq += __shfl_xor(sq, 1, 16);
        sum += __shfl_xor(sum, 2, 16); sq += __shfl_xor(sq, 2, 16);
        sum += __shfl_xor(sum, 4, 16); sq += __shfl_xor(sq, 4, 16);
        sum += __shfl_xor(sum, 8, 16); sq += __shfl_xor(sq, 8, 16);
        float mu  = sum * (1.f / 512.f);
        float var = sq * (1.f / 512.f) - mu * mu;
        float inv = rsqrtf(var + 1e-5f);
        float* orow = out + (size_t)(row0 + r) * CD;
#pragma unroll
        for (int j = 0; j < 8; j++) {
            int d = tr * 4 + j * 64;
            float4 g  = *(const float4*)(lng + d);
            float4 bb = *(const float4*)(lnb + d);
            float4 v = vals[j];
            float4 o;
            o.x = (v.x - mu) * inv * g.x + bb.x;
            o.y = (v.y - mu) * inv * g.y + bb.y;
            o.z = (v.z - mu) * inv * g.z + bb.z;
            o.w = (v.w - mu) * inv * g.w + bb.w;
            *(float4*)(orow + d) = o;
        }
    }
}

// ---------------------------------------------------------------------------
extern "C" void kernel_launch(void* const* d_in, const int* in_sizes, int n_in,
                              void* d_out, int out_size, void* d_ws, size_t ws_size,
                              hipStream_t stream) {
    (void)in_sizes; (void)n_in; (void)out_size;
    const float* X     = (const float*)d_in[0];
    const float* dist  = (const float*)d_in[1];
    const float* mask  = (const float*)d_in[2];
    const float* speed = (const float*)d_in[3];
    const float* Wq    = (const float*)d_in[4];
    const float* bq    = (const float*)d_in[5];
    const float* Wk    = (const float*)d_in[6];
    const float* bk    = (const float*)d_in[7];
    const float* Wv    = (const float*)d_in[8];
    const float* bv    = (const float*)d_in[9];
    const float* Weq   = (const float*)d_in[10];
    const float* beq   = (const float*)d_in[11];
    const float* Wd1   = (const float*)d_in[16];
    const float* bd1   = (const float*)d_in[17];
    const float* Wd2   = (const float*)d_in[18];
    const float* bd2   = (const float*)d_in[19];
    const float* lng   = (const float*)d_in[20];
    const float* lnb   = (const float*)d_in[21];
    float* out = (float*)d_out;

    char* ws = (char*)d_ws;
    int*   Kp       = (int*)(ws);
    int*   candIdx  = (int*)(ws + 256);
    float* candDist = (float*)(ws + 1024);
    float* S0       = (float*)(ws + 2048);                 // 7168 B
    unsigned short* VcB = (unsigned short*)(ws + 245760);  // 114688 B (bf16)
    unsigned short* Y   = (unsigned short*)(ws + 475136);  // 1835008 B (Y2 layout)
    unsigned short* WkT = (unsigned short*)(ws + 2310144); // 524288 B
    unsigned short* WvT = (unsigned short*)(ws + 2834432); // 524288 B
    unsigned short* X2  = (unsigned short*)(ws + 3358720); // 16777216 B (optional)
    int useX2 = (ws_size >= (size_t)3358720 + 16777216) ? 1 : 0;

    k_pre<<<145, 256, 0, stream>>>(dist, speed, Wk, Wv, Kp, candIdx, candDist, WkT, WvT);
    int midBlocks = 640 + (useX2 ? 512 : 0);
    k_mid<<<midBlocks, 256, 0, stream>>>(X, WkT, bk, WvT, bv, Wq, bq, Weq, beq,
                                         candIdx, VcB, S0, Y, X2);
    k_attn<<<CB * (CN / RB), 512, 0, stream>>>(X, dist, mask, Wd1, bd1, Wd2, bd2, lng, lnb,
                                               Kp, candIdx, candDist, VcB, S0, Y,
                                               X2, useX2, out);
}

// Round 19
// 70.849 us; speedup vs baseline: 1.1416x; 1.0462x over previous
//
#include <hip/hip_runtime.h>
#include <math.h>

constexpr int CB  = 16;
constexpr int CN  = 1024;
constexpr int CD  = 512;
constexpr int KM1 = 7;      // K_MAX + 1 candidate slots per batch
constexpr int RB  = 32;     // rows per k_attn block

typedef __attribute__((ext_vector_type(8))) short bf8;
typedef __attribute__((ext_vector_type(4))) float f32x4;
typedef __attribute__((ext_vector_type(4))) unsigned short us4;

__device__ inline float bf2f(unsigned short u) {
    union { unsigned int i; float f; } v; v.i = ((unsigned)u) << 16; return v.f;
}
__device__ inline unsigned short f2bf(float f) {
    union { unsigned int i; float f; } v; v.f = f;
    unsigned r = v.i + 0x7FFFu + ((v.i >> 16) & 1u);
    return (unsigned short)(r >> 16);
}
// packed f32->bf16 (RNE) via HW instruction
__device__ inline unsigned int cvtpk(float lo, float hi) {
    unsigned int r;
    asm("v_cvt_pk_bf16_f32 %0, %1, %2" : "=v"(r) : "v"(lo), "v"(hi));
    return r;
}
__device__ inline bf8 pack8(float4 x, float4 y) {
    union { bf8 v; unsigned int u[4]; } r;
    r.u[0] = cvtpk(x.x, x.y); r.u[1] = cvtpk(x.z, x.w);
    r.u[2] = cvtpk(y.x, y.y); r.u[3] = cvtpk(y.z, y.w);
    return r.v;
}
__device__ inline us4 pack4(float4 x) {
    union { us4 v; unsigned int u[2]; } r;
    r.u[0] = cvtpk(x.x, x.y); r.u[1] = cvtpk(x.z, x.w);
    return r.v;
}

// ---------------------------------------------------------------------------
// Kernel PRE: blocks 0..15 top-7 (wave-parallel packed-min) |
// 16..143 transW | 144 computeK.
// ---------------------------------------------------------------------------
__global__ __launch_bounds__(256) void k_pre(
    const float* __restrict__ dist, const float* __restrict__ speed,
    const float* __restrict__ Wk, const float* __restrict__ Wv,
    int* __restrict__ Kout,
    int* __restrict__ candIdx, float* __restrict__ candDist,
    unsigned short* __restrict__ WkT, unsigned short* __restrict__ WvT) {
    int t = threadIdx.x;
    int bid = blockIdx.x;

    if (bid < 16) {
        __shared__ float sdist[CN];
        __shared__ unsigned long long red64[4];
        int b = bid;
        for (int i = t; i < CN; i += 256) sdist[i] = dist[b * CN + i];
        __syncthreads();
        for (int sel = 0; sel < KM1; sel++) {
            unsigned long long best = 0xFFFFFFFFFFFFFFFFull;
            for (int i = t; i < CN; i += 256) {
                unsigned long long key =
                    ((unsigned long long)__float_as_uint(sdist[i]) << 32) | (unsigned)i;
                best = best < key ? best : key;
            }
#pragma unroll
            for (int off = 32; off; off >>= 1) {
                unsigned long long o = __shfl_xor(best, off);
                best = best < o ? best : o;
            }
            if ((t & 63) == 0) red64[t >> 6] = best;
            __syncthreads();
            if (t == 0) {
                unsigned long long m0 = red64[0] < red64[1] ? red64[0] : red64[1];
                unsigned long long m1 = red64[2] < red64[3] ? red64[2] : red64[3];
                unsigned long long m = m0 < m1 ? m0 : m1;
                int idx = (int)(unsigned)(m & 0xFFFFFFFFu);
                candIdx[b * KM1 + sel]  = idx;
                candDist[b * KM1 + sel] = __uint_as_float((unsigned)(m >> 32));
                sdist[idx] = 3.4e38f;
            }
            __syncthreads();
        }
        return;
    }
    if (bid < 144) {
        __shared__ unsigned short tile[64][68];
        int b2 = bid - 16;
        int kt = b2 & 7, ct = (b2 >> 3) & 7, mat = b2 >> 6;
        const float* W = mat ? Wv : Wk;
        unsigned short* WT = mat ? WvT : WkT;
        int k0 = kt * 64, c0 = ct * 64;
#pragma unroll
        for (int p = 0; p < 4; p++) {
            int kr = p * 16 + (t >> 4);
            int cc = (t & 15) * 4;
            float4 v = *(const float4*)(W + (size_t)(k0 + kr) * CD + c0 + cc);
            *(us4*)&tile[kr][cc] = pack4(v);
        }
        __syncthreads();
#pragma unroll
        for (int p = 0; p < 4; p++) {
            int cr = p * 16 + (t >> 4);
            int kk = (t & 15) * 4;
            us4 o;
            o.x = tile[kk + 0][cr];
            o.y = tile[kk + 1][cr];
            o.z = tile[kk + 2][cr];
            o.w = tile[kk + 3][cr];
            *(us4*)(WT + (size_t)(c0 + cr) * CD + k0 + kk) = o;
        }
        return;
    }
    {
        __shared__ int red[256];
        int cnt = 0;
        for (int i = t; i < CB * CN; i += 256) cnt += (dist[i] < 20.0f) ? 1 : 0;
        red[t] = cnt;
        __syncthreads();
        for (int s = 128; s > 0; s >>= 1) {
            if (t < s) red[t] += red[t + s];
            __syncthreads();
        }
        if (t == 0) {
            float ss = 0.f;
            for (int i = 0; i < CB; i++) ss += speed[i];
            int K = 4;
            if (ss / (float)CB > 15.0f) K = (K + 1 > 6) ? 6 : K + 1;
            float density = (float)red[0] / (float)(CB * CN);
            if (density > 0.5f) K = (K + 1 > 6) ? 6 : K + 1;
            if (K > CN - 1) K = CN - 1;
            if (K < 0) K = 0;
            *Kout = K;
        }
    }
}

// ---------------------------------------------------------------------------
// Kernel MID: bid<128 -> Vc blocks (b,ny) writing bf16 Vc;
// 128..383 -> Y blocks (b,h,half) recomputing their 7x64 Kc slice locally;
// bid>=384 -> X2 fragment-major repack.
// ---------------------------------------------------------------------------
__global__ __launch_bounds__(256) void k_mid(
    const float* __restrict__ X,
    const unsigned short* __restrict__ WkT, const float* __restrict__ bk,
    const unsigned short* __restrict__ WvT, const float* __restrict__ bv,
    const float* __restrict__ Wq, const float* __restrict__ bq,
    const float* __restrict__ Weq, const float* __restrict__ beq,
    const int* __restrict__ candIdx,
    unsigned short* __restrict__ VcB, float* __restrict__ S0,
    unsigned short* __restrict__ Y,
    unsigned short* __restrict__ X2) {
    int t = threadIdx.x;
    int bid = blockIdx.x;
    __shared__ unsigned short sbuf[RB][520];   // repack: 32 rows; Vc/Y: rows 0..15

    if (bid >= 384) {
        int tileId = bid - 384;                  // 0..511 == k_attn logical bid
        int b = tileId >> 5, rblk = tileId & 31;
        int row0 = b * CN + rblk * RB;
        for (int idx = t; idx < RB * 128; idx += 256) {
            int r = idx >> 7, c4 = idx & 127;
            float4 xv = *(const float4*)(X + (size_t)(row0 + r) * CD + c4 * 4);
            *(us4*)&sbuf[r][c4 * 4] = pack4(xv);
        }
        __syncthreads();
        unsigned short* dst = X2 + (size_t)tileId * 16384;
#pragma unroll
        for (int it = 0; it < 8; it++) {
            int unit = t + it * 256;            // unit = s*128 + kg*32 + r
            int r = unit & 31, kg = (unit >> 5) & 3, s = unit >> 7;
            const unsigned short* src = &sbuf[r][s * 32 + kg * 8];
            us4 lo = *(const us4*)src;
            us4 hi = *(const us4*)(src + 4);
            *(us4*)(dst + (size_t)unit * 8)     = lo;
            *(us4*)(dst + (size_t)unit * 8 + 4) = hi;
        }
        return;
    }

    int b = (bid < 128) ? (bid >> 3) : ((bid - 128) >> 4);
    for (int i = t; i < 16 * 128; i += 256) {
        int m = i >> 7, c4 = i & 127;
        float4 xv = {0.f, 0.f, 0.f, 0.f};
        if (m < KM1)
            xv = *(const float4*)(X + (size_t)(b * CN + candIdx[b * KM1 + m]) * CD + c4 * 4);
        *(us4*)&sbuf[m][c4 * 4] = pack4(xv);
    }
    __syncthreads();

    int w = t >> 6, lane = t & 63, lr = lane & 15, kg = lane >> 4;

    if (bid < 128) {
        int ny = bid & 7;
        int c = ny * 64 + w * 16 + lr;
        const unsigned short* wtp = WvT + (size_t)c * CD + kg * 8;
        f32x4 acc = {0.f, 0.f, 0.f, 0.f};
#pragma unroll
        for (int s = 0; s < 16; s++) {
            bf8 bfr = *(const bf8*)(wtp + s * 32);
            bf8 a   = *(const bf8*)&sbuf[lr][s * 32 + kg * 8];
            acc = __builtin_amdgcn_mfma_f32_16x16x32_bf16(a, bfr, acc, 0, 0, 0);
        }
        float bv_ = bv[c];
#pragma unroll
        for (int q = 0; q < 4; q++) {
            int m = kg * 4 + q;
            if (m < KM1)
                VcB[(size_t)(b * KM1 + m) * CD + c] = f2bf(acc[q] + bv_);
        }
        return;
    }

    int rem = (bid - 128) & 15;
    int h = rem >> 1, half = rem & 1;
    __shared__ unsigned short sKc16[16][68];
    __shared__ float sKcf[KM1][64];

    {
        int c = h * 64 + w * 16 + lr;
        const unsigned short* wtp = WkT + (size_t)c * CD + kg * 8;
        f32x4 acc = {0.f, 0.f, 0.f, 0.f};
#pragma unroll
        for (int s = 0; s < 16; s++) {
            bf8 bfr = *(const bf8*)(wtp + s * 32);
            bf8 a   = *(const bf8*)&sbuf[lr][s * 32 + kg * 8];
            acc = __builtin_amdgcn_mfma_f32_16x16x32_bf16(a, bfr, acc, 0, 0, 0);
        }
        float bk_ = bk[c];
        int cl = w * 16 + lr;
#pragma unroll
        for (int q = 0; q < 4; q++) {
            int m = kg * 4 + q;
            float val = (m < KM1) ? (acc[q] + bk_) : 0.f;
            sKc16[m][cl] = f2bf(val);
            if (m < KM1) sKcf[m][cl] = val;
        }
    }
    __syncthreads();

    if (half == 0 && t < 14) {
        int mat = t / 7, m = t % 7;
        const float* bias = mat ? beq : bq;
        float s = 0.f;
        for (int c = 0; c < 64; c++) s = fmaf(bias[h * 64 + c], sKcf[m][c], s);
        S0[((b * 2 + mat) * KM1 + m) * 8 + h] = s;
    }

    bf8 a0 = *(const bf8*)&sKc16[lr][kg * 8];
    bf8 a1 = *(const bf8*)&sKc16[lr][32 + kg * 8];
    unsigned short* Y2b = Y + (size_t)b * 64 * 112 * 8;
#pragma unroll
    for (int mat = 0; mat < 2; mat++) {
        const float* W = mat ? Weq : Wq;
#pragma unroll
        for (int nt = 0; nt < 4; nt++) {
            int n0 = (half * 16 + w * 4 + nt) * 16;
            const float* wp = W + (size_t)(n0 + lr) * CD + h * 64 + kg * 8;
            float4 f0 = *(const float4*)(wp);
            float4 f1 = *(const float4*)(wp + 4);
            float4 f2 = *(const float4*)(wp + 32);
            float4 f3 = *(const float4*)(wp + 36);
            f32x4 acc = {0.f, 0.f, 0.f, 0.f};
            acc = __builtin_amdgcn_mfma_f32_16x16x32_bf16(a0, pack8(f0, f1), acc, 0, 0, 0);
            acc = __builtin_amdgcn_mfma_f32_16x16x32_bf16(a1, pack8(f2, f3), acc, 0, 0, 0);
            int k_out = n0 + lr;
            int k8 = k_out >> 3, krem = k_out & 7;
#pragma unroll
            for (int q = 0; q < 4; q++) {
                int m = kg * 4 + q;
                if (m < KM1) {
                    int n = mat * 56 + m * 8 + h;
                    Y2b[((size_t)k8 * 112 + n) * 8 + krem] = f2bf(acc[q]);
                }
            }
        }
    }
}

// ---------------------------------------------------------------------------
// Kernel attn: 512 threads/block, 32 rows/block, grid 512.
//   XCD-aware block swizzle: logical = (hw%8)*64 + hw/8 (bijective, 512=8*64)
//   -> each XCD's L2 serves 2 batches' Y/Vc panels.
//   Waves 0-3: score MFMA (B1, A-frags from X2, s_setprio-boosted).
//   Waves 4-7: bias MLP (B2).  Fused blend+softmax+W7 (D); PV + LN (E).
// ---------------------------------------------------------------------------
__global__ __launch_bounds__(512) void k_attn(
    const float* __restrict__ X, const float* __restrict__ dist,
    const float* __restrict__ mask,
    const float* __restrict__ Wd1, const float* __restrict__ bd1,
    const float* __restrict__ Wd2, const float* __restrict__ bd2,
    const float* __restrict__ lng, const float* __restrict__ lnb,
    const int* __restrict__ Kp, const int* __restrict__ candIdx,
    const float* __restrict__ candDist,
    const unsigned short* __restrict__ VcB, const float* __restrict__ S0,
    const unsigned short* __restrict__ Y,
    const unsigned short* __restrict__ X2, int useX2,
    float* __restrict__ out) {

    __shared__ float sS[RB][116];
    __shared__ unsigned short sVc[KM1][520];
    __shared__ float sW7[RB][8][8];
    __shared__ float sBias[RB][6][2][8];
    __shared__ int   snbr[RB][6];
    __shared__ float skd[RB][6];
    __shared__ float srd[RB];
    __shared__ float sE[RB];
    __shared__ float sS0[112];

    int t = threadIdx.x;
    // XCD-aware swizzle (bijective: 512 = 8 XCDs x 64 chunks)
    int hw = blockIdx.x;
    int bid = (hw & 7) * 64 + (hw >> 3);
    int b = bid >> 5, rblk = bid & 31;
    int row0 = b * CN + rblk * RB;
    int K = *Kp;

    for (int idx = t; idx < KM1 * 128; idx += 512) {
        int m = idx >> 7, c4 = idx & 127;
        *(us4*)&sVc[m][c4 * 4] =
            *(const us4*)(VcB + (size_t)(b * KM1 + m) * CD + c4 * 4);
    }
    if (t < 112) sS0[t] = S0[b * 112 + t];
    if (t < RB) {
        int i = rblk * RB + t;
        sE[t]  = mask[b * CN + i];
        srd[t] = dist[b * CN + i];
        int cnt = 0;
        for (int m = 0; m <= K && cnt < K; m++) {
            int c = candIdx[b * KM1 + m];
            if (c != i) { snbr[t][cnt] = m; skd[t][cnt] = candDist[b * KM1 + m]; cnt++; }
        }
    }
    __syncthreads();

    int w = t >> 6;
    if (w < 4) {
        int lane = t & 63, lr = lane & 15, kg = lane >> 4;
        f32x4 acc00 = {0.f, 0.f, 0.f, 0.f}, acc10 = acc00, acc01 = acc00, acc11 = acc00;
        bool has2 = (w < 3);
        const unsigned short* ypk = Y + ((size_t)b * 64 * 112 + (size_t)kg * 112 + (w * 16 + lr)) * 8;
        __builtin_amdgcn_s_setprio(1);
        if (useX2) {
            const unsigned short* x2s = X2 + (size_t)bid * 16384 + kg * 256 + lr * 8;
#pragma unroll
            for (int s = 0; s < 16; s++) {
                const unsigned short* xp = x2s + s * 1024;
                bf8 a0 = *(const bf8*)xp;
                bf8 a1 = *(const bf8*)(xp + 128);
                const unsigned short* ys = ypk + (size_t)s * 4 * 112 * 8;
                bf8 b0 = *(const bf8*)ys;
                acc00 = __builtin_amdgcn_mfma_f32_16x16x32_bf16(a0, b0, acc00, 0, 0, 0);
                acc10 = __builtin_amdgcn_mfma_f32_16x16x32_bf16(a1, b0, acc10, 0, 0, 0);
                if (has2) {
                    bf8 b1 = *(const bf8*)(ys + 512);
                    acc01 = __builtin_amdgcn_mfma_f32_16x16x32_bf16(a0, b1, acc01, 0, 0, 0);
                    acc11 = __builtin_amdgcn_mfma_f32_16x16x32_bf16(a1, b1, acc11, 0, 0, 0);
                }
            }
        } else {
            const float* x0 = X + (size_t)(row0 + lr) * CD + kg * 8;
            const float* x1 = X + (size_t)(row0 + 16 + lr) * CD + kg * 8;
#pragma unroll
            for (int s = 0; s < 16; s++) {
                int k0 = s * 32;
                float4 xa0 = *(const float4*)(x0 + k0);
                float4 xb0 = *(const float4*)(x0 + k0 + 4);
                float4 xa1 = *(const float4*)(x1 + k0);
                float4 xb1 = *(const float4*)(x1 + k0 + 4);
                bf8 a0 = pack8(xa0, xb0);
                bf8 a1 = pack8(xa1, xb1);
                const unsigned short* ys = ypk + (size_t)s * 4 * 112 * 8;
                bf8 b0 = *(const bf8*)ys;
                acc00 = __builtin_amdgcn_mfma_f32_16x16x32_bf16(a0, b0, acc00, 0, 0, 0);
                acc10 = __builtin_amdgcn_mfma_f32_16x16x32_bf16(a1, b0, acc10, 0, 0, 0);
                if (has2) {
                    bf8 b1 = *(const bf8*)(ys + 512);
                    acc01 = __builtin_amdgcn_mfma_f32_16x16x32_bf16(a0, b1, acc01, 0, 0, 0);
                    acc11 = __builtin_amdgcn_mfma_f32_16x16x32_bf16(a1, b1, acc11, 0, 0, 0);
                }
            }
        }
        __builtin_amdgcn_s_setprio(0);
        int n0 = w * 16 + lr;
#pragma unroll
        for (int q = 0; q < 4; q++) {
            sS[kg * 4 + q][n0]      = acc00[q];
            sS[16 + kg * 4 + q][n0] = acc10[q];
        }
        if (has2) {
            int n1 = (w + 4) * 16 + lr;
#pragma unroll
            for (int q = 0; q < 4; q++) {
                sS[kg * 4 + q][n1]      = acc01[q];
                sS[16 + kg * 4 + q][n1] = acc11[q];
            }
        }
    } else {
        int tot2 = RB * K * 2;
        for (int task = t - 256; task < tot2; task += 256) {
            int half = task & 1;
            int pid = task >> 1;
            int r = pid / K, k = pid - r * K;
            int j0 = half * 64;
            float qd = srd[r], kd = skd[r][k];
            float bacc[8];
#pragma unroll
            for (int h = 0; h < 8; h++) bacc[h] = 0.f;
            for (int j = j0; j < j0 + 64; j++) {
                float hid = fmaf(qd, Wd1[j], fmaf(kd, Wd1[128 + j], bd1[j]));
                hid = fmaxf(hid, 0.f);
                float4 wa = *(const float4*)(Wd2 + j * 8);
                float4 wb = *(const float4*)(Wd2 + j * 8 + 4);
                bacc[0] = fmaf(hid, wa.x, bacc[0]);
                bacc[1] = fmaf(hid, wa.y, bacc[1]);
                bacc[2] = fmaf(hid, wa.z, bacc[2]);
                bacc[3] = fmaf(hid, wa.w, bacc[3]);
                bacc[4] = fmaf(hid, wb.x, bacc[4]);
                bacc[5] = fmaf(hid, wb.y, bacc[5]);
                bacc[6] = fmaf(hid, wb.z, bacc[6]);
                bacc[7] = fmaf(hid, wb.w, bacc[7]);
            }
#pragma unroll
            for (int h = 0; h < 8; h++) sBias[r][k][half][h] = bacc[h];
        }
    }
    __syncthreads();

    // ---- phase D (fused blend + softmax + W7, all in registers)
    if (t < RB * 8) {
        int r = t >> 3, h = t & 7;
        float e = sE[r];
        float wv[6];
#pragma unroll
        for (int k = 0; k < 6; k++) {
            if (k < K) {
                int m = snbr[r][k];
                float scq = sS[r][m * 8 + h]      + sS0[m * 8 + h];
                float sce = sS[r][56 + m * 8 + h] + sS0[56 + m * 8 + h];
                float sc = (1.f - e) * scq + e * sce;
                float bias = sBias[r][k][0][h] + sBias[r][k][1][h] + bd2[h];
                wv[k] = sc * 0.125f * bias;
            } else {
                wv[k] = -3.4e38f;
            }
        }
        float mx = -3.4e38f;
#pragma unroll
        for (int k = 0; k < 6; k++) mx = fmaxf(mx, wv[k]);
        float sum = 0.f;
#pragma unroll
        for (int k = 0; k < 6; k++) {
            wv[k] = __expf(wv[k] - mx);
            sum += wv[k];
        }
        float inv = 1.f / sum;
#pragma unroll
        for (int m = 0; m < KM1; m++) {
            float acc = 0.f;
#pragma unroll
            for (int k = 0; k < 6; k++) {
                bool use = (k < K) && (snbr[r][k] == m);
                acc += use ? wv[k] * inv : 0.f;
            }
            sW7[r][h][m] = acc;
        }
    }
    __syncthreads();

    // ---- phase E: PV (fixed 7-slot loop) + residual + LN (16 thr/row, h=j)
    {
        int r = t >> 4, tr = t & 15;
        const float* xrow = X + (size_t)(row0 + r) * CD;
        float4 vals[8];
        float sum = 0.f, sq = 0.f;
#pragma unroll
        for (int j = 0; j < 8; j++) {
            int d = tr * 4 + j * 64;    // head h = j
            float ax = 0.f, ay = 0.f, az = 0.f, aw = 0.f;
#pragma unroll
            for (int m = 0; m < KM1; m++) {
                float wgt = sW7[r][j][m];
                us4 vv = *(const us4*)&sVc[m][d];
                ax = fmaf(wgt, bf2f(vv.x), ax);
                ay = fmaf(wgt, bf2f(vv.y), ay);
                az = fmaf(wgt, bf2f(vv.z), az);
                aw = fmaf(wgt, bf2f(vv.w), aw);
            }
            float4 xv = *(const float4*)(xrow + d);
            float4 v;
            v.x = xv.x + ax; v.y = xv.y + ay; v.z = xv.z + az; v.w = xv.w + aw;
            vals[j] = v;
            sum += v.x + v.y + v.z + v.w;
            sq = fmaf(v.x, v.x, sq); sq = fmaf(v.y, v.y, sq);
            sq = fmaf(v.z, v.z, sq); sq = fmaf(v.w, v.w, sq);
        }
        sum += __shfl_xor(sum, 1, 16); sq += __shfl_xor(sq, 1, 16);
        sum += __shfl_xor(sum, 2, 16); sq += __shfl_xor(sq, 2, 16);
        sum += __shfl_xor(sum, 4, 16); sq += __shfl_xor(sq, 4, 16);
        sum += __shfl_xor(sum, 8, 16); sq += __shfl_xor(sq, 8, 16);
        float mu  = sum * (1.f / 512.f);
        float var = sq * (1.f / 512.f) - mu * mu;
        float inv = rsqrtf(var + 1e-5f);
        float* orow = out + (size_t)(row0 + r) * CD;
#pragma unroll
        for (int j = 0; j < 8; j++) {
            int d = tr * 4 + j * 64;
            float4 g  = *(const float4*)(lng + d);
            float4 bb = *(const float4*)(lnb + d);
            float4 v = vals[j];
            float4 o;
            o.x = (v.x - mu) * inv * g.x + bb.x;
            o.y = (v.y - mu) * inv * g.y + bb.y;
            o.z = (v.z - mu) * inv * g.z + bb.z;
            o.w = (v.w - mu) * inv * g.w + bb.w;
            *(float4*)(orow + d) = o;
        }
    }
}

// ---------------------------------------------------------------------------
extern "C" void kernel_launch(void* const* d_in, const int* in_sizes, int n_in,
                              void* d_out, int out_size, void* d_ws, size_t ws_size,
                              hipStream_t stream) {
    (void)in_sizes; (void)n_in; (void)out_size;
    const float* X     = (const float*)d_in[0];
    const float* dist  = (const float*)d_in[1];
    const float* mask  = (const float*)d_in[2];
    const float* speed = (const float*)d_in[3];
    const float* Wq    = (const float*)d_in[4];
    const float* bq    = (const float*)d_in[5];
    const float* Wk    = (const float*)d_in[6];
    const float* bk    = (const float*)d_in[7];
    const float* Wv    = (const float*)d_in[8];
    const float* bv    = (const float*)d_in[9];
    const float* Weq   = (const float*)d_in[10];
    const float* beq   = (const float*)d_in[11];
    const float* Wd1   = (const float*)d_in[16];
    const float* bd1   = (const float*)d_in[17];
    const float* Wd2   = (const float*)d_in[18];
    const float* bd2   = (const float*)d_in[19];
    const float* lng   = (const float*)d_in[20];
    const float* lnb   = (const float*)d_in[21];
    float* out = (float*)d_out;

    char* ws = (char*)d_ws;
    int*   Kp       = (int*)(ws);
    int*   candIdx  = (int*)(ws + 256);
    float* candDist = (float*)(ws + 1024);
    float* S0       = (float*)(ws + 2048);                 // 7168 B
    unsigned short* VcB = (unsigned short*)(ws + 245760);  // 114688 B (bf16)
    unsigned short* Y   = (unsigned short*)(ws + 475136);  // 1835008 B (Y2 layout)
    unsigned short* WkT = (unsigned short*)(ws + 2310144); // 524288 B
    unsigned short* WvT = (unsigned short*)(ws + 2834432); // 524288 B
    unsigned short* X2  = (unsigned short*)(ws + 3358720); // 16777216 B (optional)
    int useX2 = (ws_size >= (size_t)3358720 + 16777216) ? 1 : 0;

    k_pre<<<145, 256, 0, stream>>>(dist, speed, Wk, Wv, Kp, candIdx, candDist, WkT, WvT);
    int midBlocks = 384 + (useX2 ? 512 : 0);
    k_mid<<<midBlocks, 256, 0, stream>>>(X, WkT, bk, WvT, bv, Wq, bq, Weq, beq,
                                         candIdx, VcB, S0, Y, X2);
    k_attn<<<CB * (CN / RB), 512, 0, stream>>>(X, dist, mask, Wd1, bd1, Wd2, bd2, lng, lnb,
                                               Kp, candIdx, candDist, VcB, S0, Y,
                                               X2, useX2, out);
}

// Round 20
// 67.906 us; speedup vs baseline: 1.1911x; 1.0433x over previous
//
#include <hip/hip_runtime.h>
#include <math.h>

constexpr int CB  = 16;
constexpr int CN  = 1024;
constexpr int CD  = 512;
constexpr int KM1 = 7;      // K_MAX + 1 candidate slots per batch
constexpr int RB  = 32;     // rows per k_attn block

typedef __attribute__((ext_vector_type(8))) short bf8;
typedef __attribute__((ext_vector_type(4))) float f32x4;
typedef __attribute__((ext_vector_type(4))) unsigned short us4;

__device__ inline float bf2f(unsigned short u) {
    union { unsigned int i; float f; } v; v.i = ((unsigned)u) << 16; return v.f;
}
__device__ inline unsigned short f2bf(float f) {
    union { unsigned int i; float f; } v; v.f = f;
    unsigned r = v.i + 0x7FFFu + ((v.i >> 16) & 1u);
    return (unsigned short)(r >> 16);
}
// packed f32->bf16 (RNE) via HW instruction
__device__ inline unsigned int cvtpk(float lo, float hi) {
    unsigned int r;
    asm("v_cvt_pk_bf16_f32 %0, %1, %2" : "=v"(r) : "v"(lo), "v"(hi));
    return r;
}
__device__ inline bf8 pack8(float4 x, float4 y) {
    union { bf8 v; unsigned int u[4]; } r;
    r.u[0] = cvtpk(x.x, x.y); r.u[1] = cvtpk(x.z, x.w);
    r.u[2] = cvtpk(y.x, y.y); r.u[3] = cvtpk(y.z, y.w);
    return r.v;
}
__device__ inline us4 pack4(float4 x) {
    union { us4 v; unsigned int u[2]; } r;
    r.u[0] = cvtpk(x.x, x.y); r.u[1] = cvtpk(x.z, x.w);
    return r.v;
}

// ---------------------------------------------------------------------------
// Kernel PRE: blocks 0..15 top-7 (wave-parallel packed-min) |
// 16..143 transW | 144 computeK.
// ---------------------------------------------------------------------------
__global__ __launch_bounds__(256) void k_pre(
    const float* __restrict__ dist, const float* __restrict__ speed,
    const float* __restrict__ Wk, const float* __restrict__ Wv,
    int* __restrict__ Kout,
    int* __restrict__ candIdx, float* __restrict__ candDist,
    unsigned short* __restrict__ WkT, unsigned short* __restrict__ WvT) {
    int t = threadIdx.x;
    int bid = blockIdx.x;

    if (bid < 16) {
        __shared__ float sdist[CN];
        __shared__ unsigned long long red64[4];
        int b = bid;
        for (int i = t; i < CN; i += 256) sdist[i] = dist[b * CN + i];
        __syncthreads();
        for (int sel = 0; sel < KM1; sel++) {
            unsigned long long best = 0xFFFFFFFFFFFFFFFFull;
            for (int i = t; i < CN; i += 256) {
                unsigned long long key =
                    ((unsigned long long)__float_as_uint(sdist[i]) << 32) | (unsigned)i;
                best = best < key ? best : key;
            }
#pragma unroll
            for (int off = 32; off; off >>= 1) {
                unsigned long long o = __shfl_xor(best, off);
                best = best < o ? best : o;
            }
            if ((t & 63) == 0) red64[t >> 6] = best;
            __syncthreads();
            if (t == 0) {
                unsigned long long m0 = red64[0] < red64[1] ? red64[0] : red64[1];
                unsigned long long m1 = red64[2] < red64[3] ? red64[2] : red64[3];
                unsigned long long m = m0 < m1 ? m0 : m1;
                int idx = (int)(unsigned)(m & 0xFFFFFFFFu);
                candIdx[b * KM1 + sel]  = idx;
                candDist[b * KM1 + sel] = __uint_as_float((unsigned)(m >> 32));
                sdist[idx] = 3.4e38f;
            }
            __syncthreads();
        }
        return;
    }
    if (bid < 144) {
        __shared__ unsigned short tile[64][68];
        int b2 = bid - 16;
        int kt = b2 & 7, ct = (b2 >> 3) & 7, mat = b2 >> 6;
        const float* W = mat ? Wv : Wk;
        unsigned short* WT = mat ? WvT : WkT;
        int k0 = kt * 64, c0 = ct * 64;
#pragma unroll
        for (int p = 0; p < 4; p++) {
            int kr = p * 16 + (t >> 4);
            int cc = (t & 15) * 4;
            float4 v = *(const float4*)(W + (size_t)(k0 + kr) * CD + c0 + cc);
            *(us4*)&tile[kr][cc] = pack4(v);
        }
        __syncthreads();
#pragma unroll
        for (int p = 0; p < 4; p++) {
            int cr = p * 16 + (t >> 4);
            int kk = (t & 15) * 4;
            us4 o;
            o.x = tile[kk + 0][cr];
            o.y = tile[kk + 1][cr];
            o.z = tile[kk + 2][cr];
            o.w = tile[kk + 3][cr];
            *(us4*)(WT + (size_t)(c0 + cr) * CD + k0 + kk) = o;
        }
        return;
    }
    {
        __shared__ int red[256];
        int cnt = 0;
        for (int i = t; i < CB * CN; i += 256) cnt += (dist[i] < 20.0f) ? 1 : 0;
        red[t] = cnt;
        __syncthreads();
        for (int s = 128; s > 0; s >>= 1) {
            if (t < s) red[t] += red[t + s];
            __syncthreads();
        }
        if (t == 0) {
            float ss = 0.f;
            for (int i = 0; i < CB; i++) ss += speed[i];
            int K = 4;
            if (ss / (float)CB > 15.0f) K = (K + 1 > 6) ? 6 : K + 1;
            float density = (float)red[0] / (float)(CB * CN);
            if (density > 0.5f) K = (K + 1 > 6) ? 6 : K + 1;
            if (K > CN - 1) K = CN - 1;
            if (K < 0) K = 0;
            *Kout = K;
        }
    }
}

// ---------------------------------------------------------------------------
// Kernel MID: bid<128 -> Vc blocks; 128..383 -> Y blocks; X2 repack blocks
// [384, 384+nX2); bias-MLP blocks [biasBase, biasBase+64) writing
// gBias[row][k][h] (includes bd2).
// ---------------------------------------------------------------------------
__global__ __launch_bounds__(256) void k_mid(
    const float* __restrict__ X, const float* __restrict__ dist,
    const unsigned short* __restrict__ WkT, const float* __restrict__ bk,
    const unsigned short* __restrict__ WvT, const float* __restrict__ bv,
    const float* __restrict__ Wq, const float* __restrict__ bq,
    const float* __restrict__ Weq, const float* __restrict__ beq,
    const float* __restrict__ Wd1, const float* __restrict__ bd1,
    const float* __restrict__ Wd2, const float* __restrict__ bd2,
    const int* __restrict__ Kp, const int* __restrict__ candIdx,
    const float* __restrict__ candDist,
    unsigned short* __restrict__ VcB, float* __restrict__ S0,
    unsigned short* __restrict__ Y,
    unsigned short* __restrict__ X2, float* __restrict__ gBias,
    int biasBase) {
    int t = threadIdx.x;
    int bid = blockIdx.x;
    __shared__ unsigned short sbuf[RB][520];

    if (bid >= biasBase) {
        // ---- bias-MLP block: 256 rows, 1 row/thread
        int g = (bid - biasBase) * 256 + t;       // global flat row
        int b = g >> 10, i = g & 1023;
        int K = *Kp;
        float qd = dist[g];
        int   nb[6]; float kd6[6];
#pragma unroll
        for (int j = 0; j < 6; j++) { nb[j] = 0; kd6[j] = 0.f; }
        int cnt = 0;
        for (int m = 0; m <= K && cnt < K; m++) {
            int c = candIdx[b * KM1 + m];
            if (c != i) { nb[cnt] = m; kd6[cnt] = candDist[b * KM1 + m]; cnt++; }
        }
        for (int k = 0; k < K; k++) {
            float kd = kd6[k];
            float bacc[8];
#pragma unroll
            for (int h = 0; h < 8; h++) bacc[h] = bd2[h];
            for (int j = 0; j < 128; j++) {
                float hid = fmaf(qd, Wd1[j], fmaf(kd, Wd1[128 + j], bd1[j]));
                hid = fmaxf(hid, 0.f);
                float4 wa = *(const float4*)(Wd2 + j * 8);
                float4 wb = *(const float4*)(Wd2 + j * 8 + 4);
                bacc[0] = fmaf(hid, wa.x, bacc[0]);
                bacc[1] = fmaf(hid, wa.y, bacc[1]);
                bacc[2] = fmaf(hid, wa.z, bacc[2]);
                bacc[3] = fmaf(hid, wa.w, bacc[3]);
                bacc[4] = fmaf(hid, wb.x, bacc[4]);
                bacc[5] = fmaf(hid, wb.y, bacc[5]);
                bacc[6] = fmaf(hid, wb.z, bacc[6]);
                bacc[7] = fmaf(hid, wb.w, bacc[7]);
            }
            float* dst = gBias + ((size_t)g * 6 + k) * 8;
#pragma unroll
            for (int h = 0; h < 8; h++) dst[h] = bacc[h];
        }
        return;
    }

    if (bid >= 384) {
        // ---- X2 repack: one block per 32-row tile
        int tileId = bid - 384;
        int b = tileId >> 5, rblk = tileId & 31;
        int row0 = b * CN + rblk * RB;
        for (int idx = t; idx < RB * 128; idx += 256) {
            int r = idx >> 7, c4 = idx & 127;
            float4 xv = *(const float4*)(X + (size_t)(row0 + r) * CD + c4 * 4);
            *(us4*)&sbuf[r][c4 * 4] = pack4(xv);
        }
        __syncthreads();
        unsigned short* dst = X2 + (size_t)tileId * 16384;
#pragma unroll
        for (int it = 0; it < 8; it++) {
            int unit = t + it * 256;            // unit = s*128 + kg*32 + r
            int r = unit & 31, kg = (unit >> 5) & 3, s = unit >> 7;
            const unsigned short* src = &sbuf[r][s * 32 + kg * 8];
            us4 lo = *(const us4*)src;
            us4 hi = *(const us4*)(src + 4);
            *(us4*)(dst + (size_t)unit * 8)     = lo;
            *(us4*)(dst + (size_t)unit * 8 + 4) = hi;
        }
        return;
    }

    int b = (bid < 128) ? (bid >> 3) : ((bid - 128) >> 4);
    for (int i = t; i < 16 * 128; i += 256) {
        int m = i >> 7, c4 = i & 127;
        float4 xv = {0.f, 0.f, 0.f, 0.f};
        if (m < KM1)
            xv = *(const float4*)(X + (size_t)(b * CN + candIdx[b * KM1 + m]) * CD + c4 * 4);
        *(us4*)&sbuf[m][c4 * 4] = pack4(xv);
    }
    __syncthreads();

    int w = t >> 6, lane = t & 63, lr = lane & 15, kg = lane >> 4;

    if (bid < 128) {
        int ny = bid & 7;
        int c = ny * 64 + w * 16 + lr;
        const unsigned short* wtp = WvT + (size_t)c * CD + kg * 8;
        f32x4 acc = {0.f, 0.f, 0.f, 0.f};
#pragma unroll
        for (int s = 0; s < 16; s++) {
            bf8 bfr = *(const bf8*)(wtp + s * 32);
            bf8 a   = *(const bf8*)&sbuf[lr][s * 32 + kg * 8];
            acc = __builtin_amdgcn_mfma_f32_16x16x32_bf16(a, bfr, acc, 0, 0, 0);
        }
        float bv_ = bv[c];
#pragma unroll
        for (int q = 0; q < 4; q++) {
            int m = kg * 4 + q;
            if (m < KM1)
                VcB[(size_t)(b * KM1 + m) * CD + c] = f2bf(acc[q] + bv_);
        }
        return;
    }

    int rem = (bid - 128) & 15;
    int h = rem >> 1, half = rem & 1;
    __shared__ unsigned short sKc16[16][68];
    __shared__ float sKcf[KM1][64];

    {
        int c = h * 64 + w * 16 + lr;
        const unsigned short* wtp = WkT + (size_t)c * CD + kg * 8;
        f32x4 acc = {0.f, 0.f, 0.f, 0.f};
#pragma unroll
        for (int s = 0; s < 16; s++) {
            bf8 bfr = *(const bf8*)(wtp + s * 32);
            bf8 a   = *(const bf8*)&sbuf[lr][s * 32 + kg * 8];
            acc = __builtin_amdgcn_mfma_f32_16x16x32_bf16(a, bfr, acc, 0, 0, 0);
        }
        float bk_ = bk[c];
        int cl = w * 16 + lr;
#pragma unroll
        for (int q = 0; q < 4; q++) {
            int m = kg * 4 + q;
            float val = (m < KM1) ? (acc[q] + bk_) : 0.f;
            sKc16[m][cl] = f2bf(val);
            if (m < KM1) sKcf[m][cl] = val;
        }
    }
    __syncthreads();

    if (half == 0 && t < 14) {
        int mat = t / 7, m = t % 7;
        const float* bias = mat ? beq : bq;
        float s = 0.f;
        for (int c = 0; c < 64; c++) s = fmaf(bias[h * 64 + c], sKcf[m][c], s);
        S0[((b * 2 + mat) * KM1 + m) * 8 + h] = s;
    }

    bf8 a0 = *(const bf8*)&sKc16[lr][kg * 8];
    bf8 a1 = *(const bf8*)&sKc16[lr][32 + kg * 8];
    unsigned short* Y2b = Y + (size_t)b * 64 * 112 * 8;
#pragma unroll
    for (int mat = 0; mat < 2; mat++) {
        const float* W = mat ? Weq : Wq;
#pragma unroll
        for (int nt = 0; nt < 4; nt++) {
            int n0 = (half * 16 + w * 4 + nt) * 16;
            const float* wp = W + (size_t)(n0 + lr) * CD + h * 64 + kg * 8;
            float4 f0 = *(const float4*)(wp);
            float4 f1 = *(const float4*)(wp + 4);
            float4 f2 = *(const float4*)(wp + 32);
            float4 f3 = *(const float4*)(wp + 36);
            f32x4 acc = {0.f, 0.f, 0.f, 0.f};
            acc = __builtin_amdgcn_mfma_f32_16x16x32_bf16(a0, pack8(f0, f1), acc, 0, 0, 0);
            acc = __builtin_amdgcn_mfma_f32_16x16x32_bf16(a1, pack8(f2, f3), acc, 0, 0, 0);
            int k_out = n0 + lr;
            int k8 = k_out >> 3, krem = k_out & 7;
#pragma unroll
            for (int q = 0; q < 4; q++) {
                int m = kg * 4 + q;
                if (m < KM1) {
                    int n = mat * 56 + m * 8 + h;
                    Y2b[((size_t)k8 * 112 + n) * 8 + krem] = f2bf(acc[q]);
                }
            }
        }
    }
}

// ---------------------------------------------------------------------------
// Kernel attn: 512 threads/block, 32 rows/block, grid 512, XCD swizzle.
//   useBias: waves 0-6 each compute ONE n-tile of B1 (half the critical
//   path); phase D reads precomputed gBias.  Fallback: round-16 dual-wave.
// ---------------------------------------------------------------------------
__global__ __launch_bounds__(512) void k_attn(
    const float* __restrict__ X, const float* __restrict__ dist,
    const float* __restrict__ mask,
    const float* __restrict__ Wd1, const float* __restrict__ bd1,
    const float* __restrict__ Wd2, const float* __restrict__ bd2,
    const float* __restrict__ lng, const float* __restrict__ lnb,
    const int* __restrict__ Kp, const int* __restrict__ candIdx,
    const float* __restrict__ candDist,
    const unsigned short* __restrict__ VcB, const float* __restrict__ S0,
    const unsigned short* __restrict__ Y,
    const unsigned short* __restrict__ X2, int useX2,
    const float* __restrict__ gBias, int useBias,
    float* __restrict__ out) {

    __shared__ float sS[RB][116];
    __shared__ unsigned short sVc[KM1][520];
    __shared__ float sW7[RB][8][8];
    __shared__ float sBias[RB][6][2][8];
    __shared__ int   snbr[RB][6];
    __shared__ float skd[RB][6];
    __shared__ float srd[RB];
    __shared__ float sE[RB];
    __shared__ float sS0[112];

    int t = threadIdx.x;
    int hw = blockIdx.x;
    int bid = (hw & 7) * 64 + (hw >> 3);   // XCD-aware bijective swizzle
    int b = bid >> 5, rblk = bid & 31;
    int row0 = b * CN + rblk * RB;
    int K = *Kp;

    for (int idx = t; idx < KM1 * 128; idx += 512) {
        int m = idx >> 7, c4 = idx & 127;
        *(us4*)&sVc[m][c4 * 4] =
            *(const us4*)(VcB + (size_t)(b * KM1 + m) * CD + c4 * 4);
    }
    if (t < 112) sS0[t] = S0[b * 112 + t];
    if (t < RB) {
        int i = rblk * RB + t;
        sE[t]  = mask[b * CN + i];
        srd[t] = dist[b * CN + i];
        int cnt = 0;
        for (int m = 0; m <= K && cnt < K; m++) {
            int c = candIdx[b * KM1 + m];
            if (c != i) { snbr[t][cnt] = m; skd[t][cnt] = candDist[b * KM1 + m]; cnt++; }
        }
    }
    __syncthreads();

    int w = t >> 6;
    if (useBias) {
        // ---- B1 only: 7 waves, one n-tile each
        if (w < 7) {
            int lane = t & 63, lr = lane & 15, kg = lane >> 4;
            f32x4 acc00 = {0.f, 0.f, 0.f, 0.f}, acc10 = acc00;
            const unsigned short* ypk =
                Y + ((size_t)b * 64 * 112 + (size_t)kg * 112 + (w * 16 + lr)) * 8;
            __builtin_amdgcn_s_setprio(1);
            if (useX2) {
                const unsigned short* x2s =
                    X2 + (size_t)bid * 16384 + kg * 256 + lr * 8;
#pragma unroll
                for (int s = 0; s < 16; s++) {
                    const unsigned short* xp = x2s + s * 1024;
                    bf8 a0 = *(const bf8*)xp;
                    bf8 a1 = *(const bf8*)(xp + 128);
                    bf8 b0 = *(const bf8*)(ypk + (size_t)s * 4 * 112 * 8);
                    acc00 = __builtin_amdgcn_mfma_f32_16x16x32_bf16(a0, b0, acc00, 0, 0, 0);
                    acc10 = __builtin_amdgcn_mfma_f32_16x16x32_bf16(a1, b0, acc10, 0, 0, 0);
                }
            } else {
                const float* x0 = X + (size_t)(row0 + lr) * CD + kg * 8;
                const float* x1 = X + (size_t)(row0 + 16 + lr) * CD + kg * 8;
#pragma unroll
                for (int s = 0; s < 16; s++) {
                    int k0 = s * 32;
                    bf8 a0 = pack8(*(const float4*)(x0 + k0), *(const float4*)(x0 + k0 + 4));
                    bf8 a1 = pack8(*(const float4*)(x1 + k0), *(const float4*)(x1 + k0 + 4));
                    bf8 b0 = *(const bf8*)(ypk + (size_t)s * 4 * 112 * 8);
                    acc00 = __builtin_amdgcn_mfma_f32_16x16x32_bf16(a0, b0, acc00, 0, 0, 0);
                    acc10 = __builtin_amdgcn_mfma_f32_16x16x32_bf16(a1, b0, acc10, 0, 0, 0);
                }
            }
            __builtin_amdgcn_s_setprio(0);
            int n0 = w * 16 + lr;
#pragma unroll
            for (int q = 0; q < 4; q++) {
                sS[kg * 4 + q][n0]      = acc00[q];
                sS[16 + kg * 4 + q][n0] = acc10[q];
            }
        }
    } else {
        if (w < 4) {
            int lane = t & 63, lr = lane & 15, kg = lane >> 4;
            f32x4 acc00 = {0.f, 0.f, 0.f, 0.f}, acc10 = acc00, acc01 = acc00, acc11 = acc00;
            bool has2 = (w < 3);
            const unsigned short* ypk =
                Y + ((size_t)b * 64 * 112 + (size_t)kg * 112 + (w * 16 + lr)) * 8;
            __builtin_amdgcn_s_setprio(1);
            if (useX2) {
                const unsigned short* x2s = X2 + (size_t)bid * 16384 + kg * 256 + lr * 8;
#pragma unroll
                for (int s = 0; s < 16; s++) {
                    const unsigned short* xp = x2s + s * 1024;
                    bf8 a0 = *(const bf8*)xp;
                    bf8 a1 = *(const bf8*)(xp + 128);
                    const unsigned short* ys = ypk + (size_t)s * 4 * 112 * 8;
                    bf8 b0 = *(const bf8*)ys;
                    acc00 = __builtin_amdgcn_mfma_f32_16x16x32_bf16(a0, b0, acc00, 0, 0, 0);
                    acc10 = __builtin_amdgcn_mfma_f32_16x16x32_bf16(a1, b0, acc10, 0, 0, 0);
                    if (has2) {
                        bf8 b1 = *(const bf8*)(ys + 512);
                        acc01 = __builtin_amdgcn_mfma_f32_16x16x32_bf16(a0, b1, acc01, 0, 0, 0);
                        acc11 = __builtin_amdgcn_mfma_f32_16x16x32_bf16(a1, b1, acc11, 0, 0, 0);
                    }
                }
            } else {
                const float* x0 = X + (size_t)(row0 + lr) * CD + kg * 8;
                const float* x1 = X + (size_t)(row0 + 16 + lr) * CD + kg * 8;
#pragma unroll
                for (int s = 0; s < 16; s++) {
                    int k0 = s * 32;
                    bf8 a0 = pack8(*(const float4*)(x0 + k0), *(const float4*)(x0 + k0 + 4));
                    bf8 a1 = pack8(*(const float4*)(x1 + k0), *(const float4*)(x1 + k0 + 4));
                    const unsigned short* ys = ypk + (size_t)s * 4 * 112 * 8;
                    bf8 b0 = *(const bf8*)ys;
                    acc00 = __builtin_amdgcn_mfma_f32_16x16x32_bf16(a0, b0, acc00, 0, 0, 0);
                    acc10 = __builtin_amdgcn_mfma_f32_16x16x32_bf16(a1, b0, acc10, 0, 0, 0);
                    if (has2) {
                        bf8 b1 = *(const bf8*)(ys + 512);
                        acc01 = __builtin_amdgcn_mfma_f32_16x16x32_bf16(a0, b1, acc01, 0, 0, 0);
                        acc11 = __builtin_amdgcn_mfma_f32_16x16x32_bf16(a1, b1, acc11, 0, 0, 0);
                    }
                }
            }
            __builtin_amdgcn_s_setprio(0);
            int n0 = w * 16 + lr;
#pragma unroll
            for (int q = 0; q < 4; q++) {
                sS[kg * 4 + q][n0]      = acc00[q];
                sS[16 + kg * 4 + q][n0] = acc10[q];
            }
            if (has2) {
                int n1 = (w + 4) * 16 + lr;
#pragma unroll
                for (int q = 0; q < 4; q++) {
                    sS[kg * 4 + q][n1]      = acc01[q];
                    sS[16 + kg * 4 + q][n1] = acc11[q];
                }
            }
        } else {
            int tot2 = RB * K * 2;
            for (int task = t - 256; task < tot2; task += 256) {
                int half = task & 1;
                int pid = task >> 1;
                int r = pid / K, k = pid - r * K;
                int j0 = half * 64;
                float qd = srd[r], kd = skd[r][k];
                float bacc[8];
#pragma unroll
                for (int h = 0; h < 8; h++) bacc[h] = 0.f;
                for (int j = j0; j < j0 + 64; j++) {
                    float hid = fmaf(qd, Wd1[j], fmaf(kd, Wd1[128 + j], bd1[j]));
                    hid = fmaxf(hid, 0.f);
                    float4 wa = *(const float4*)(Wd2 + j * 8);
                    float4 wb = *(const float4*)(Wd2 + j * 8 + 4);
                    bacc[0] = fmaf(hid, wa.x, bacc[0]);
                    bacc[1] = fmaf(hid, wa.y, bacc[1]);
                    bacc[2] = fmaf(hid, wa.z, bacc[2]);
                    bacc[3] = fmaf(hid, wa.w, bacc[3]);
                    bacc[4] = fmaf(hid, wb.x, bacc[4]);
                    bacc[5] = fmaf(hid, wb.y, bacc[5]);
                    bacc[6] = fmaf(hid, wb.z, bacc[6]);
                    bacc[7] = fmaf(hid, wb.w, bacc[7]);
                }
#pragma unroll
                for (int h = 0; h < 8; h++) sBias[r][k][half][h] = bacc[h];
            }
        }
    }
    __syncthreads();

    // ---- phase D (fused blend + softmax + W7, all in registers)
    if (t < RB * 8) {
        int r = t >> 3, h = t & 7;
        float e = sE[r];
        const float* gb = gBias + ((size_t)(row0 + r) * 6) * 8 + h;
        float wv[6];
#pragma unroll
        for (int k = 0; k < 6; k++) {
            if (k < K) {
                int m = snbr[r][k];
                float scq = sS[r][m * 8 + h]      + sS0[m * 8 + h];
                float sce = sS[r][56 + m * 8 + h] + sS0[56 + m * 8 + h];
                float sc = (1.f - e) * scq + e * sce;
                float bias = useBias ? gb[k * 8]
                                     : (sBias[r][k][0][h] + sBias[r][k][1][h] + bd2[h]);
                wv[k] = sc * 0.125f * bias;
            } else {
                wv[k] = -3.4e38f;
            }
        }
        float mx = -3.4e38f;
#pragma unroll
        for (int k = 0; k < 6; k++) mx = fmaxf(mx, wv[k]);
        float sum = 0.f;
#pragma unroll
        for (int k = 0; k < 6; k++) {
            wv[k] = __expf(wv[k] - mx);
            sum += wv[k];
        }
        float inv = 1.f / sum;
#pragma unroll
        for (int m = 0; m < KM1; m++) {
            float acc = 0.f;
#pragma unroll
            for (int k = 0; k < 6; k++) {
                bool use = (k < K) && (snbr[r][k] == m);
                acc += use ? wv[k] * inv : 0.f;
            }
            sW7[r][h][m] = acc;
        }
    }
    __syncthreads();

    // ---- phase E: PV (fixed 7-slot loop) + residual + LN (16 thr/row, h=j)
    {
        int r = t >> 4, tr = t & 15;
        const float* xrow = X + (size_t)(row0 + r) * CD;
        float4 vals[8];
        float sum = 0.f, sq = 0.f;
#pragma unroll
        for (int j = 0; j < 8; j++) {
            int d = tr * 4 + j * 64;    // head h = j
            float ax = 0.f, ay = 0.f, az = 0.f, aw = 0.f;
#pragma unroll
            for (int m = 0; m < KM1; m++) {
                float wgt = sW7[r][j][m];
                us4 vv = *(const us4*)&sVc[m][d];
                ax = fmaf(wgt, bf2f(vv.x), ax);
                ay = fmaf(wgt, bf2f(vv.y), ay);
                az = fmaf(wgt, bf2f(vv.z), az);
                aw = fmaf(wgt, bf2f(vv.w), aw);
            }
            float4 xv = *(const float4*)(xrow + d);
            float4 v;
            v.x = xv.x + ax; v.y = xv.y + ay; v.z = xv.z + az; v.w = xv.w + aw;
            vals[j] = v;
            sum += v.x + v.y + v.z + v.w;
            sq = fmaf(v.x, v.x, sq); sq = fmaf(v.y, v.y, sq);
            sq = fmaf(v.z, v.z, sq); sq = fmaf(v.w, v.w, sq);
        }
        sum += __shfl_xor(sum, 1, 16); sq += __shfl_xor(sq, 1, 16);
        sum += __shfl_xor(sum, 2, 16); sq += __shfl_xor(sq, 2, 16);
        sum += __shfl_xor(sum, 4, 16); sq += __shfl_xor(sq, 4, 16);
        sum += __shfl_xor(sum, 8, 16); sq += __shfl_xor(sq, 8, 16);
        float mu  = sum * (1.f / 512.f);
        float var = sq * (1.f / 512.f) - mu * mu;
        float inv = rsqrtf(var + 1e-5f);
        float* orow = out + (size_t)(row0 + r) * CD;
#pragma unroll
        for (int j = 0; j < 8; j++) {
            int d = tr * 4 + j * 64;
            float4 g  = *(const float4*)(lng + d);
            float4 bb = *(const float4*)(lnb + d);
            float4 v = vals[j];
            float4 o;
            o.x = (v.x - mu) * inv * g.x + bb.x;
            o.y = (v.y - mu) * inv * g.y + bb.y;
            o.z = (v.z - mu) * inv * g.z + bb.z;
            o.w = (v.w - mu) * inv * g.w + bb.w;
            *(float4*)(orow + d) = o;
        }
    }
}

// ---------------------------------------------------------------------------
extern "C" void kernel_launch(void* const* d_in, const int* in_sizes, int n_in,
                              void* d_out, int out_size, void* d_ws, size_t ws_size,
                              hipStream_t stream) {
    (void)in_sizes; (void)n_in; (void)out_size;
    const float* X     = (const float*)d_in[0];
    const float* dist  = (const float*)d_in[1];
    const float* mask  = (const float*)d_in[2];
    const float* speed = (const float*)d_in[3];
    const float* Wq    = (const float*)d_in[4];
    const float* bq    = (const float*)d_in[5];
    const float* Wk    = (const float*)d_in[6];
    const float* bk    = (const float*)d_in[7];
    const float* Wv    = (const float*)d_in[8];
    const float* bv    = (const float*)d_in[9];
    const float* Weq   = (const float*)d_in[10];
    const float* beq   = (const float*)d_in[11];
    const float* Wd1   = (const float*)d_in[16];
    const float* bd1   = (const float*)d_in[17];
    const float* Wd2   = (const float*)d_in[18];
    const float* bd2   = (const float*)d_in[19];
    const float* lng   = (const float*)d_in[20];
    const float* lnb   = (const float*)d_in[21];
    float* out = (float*)d_out;

    char* ws = (char*)d_ws;
    int*   Kp       = (int*)(ws);
    int*   candIdx  = (int*)(ws + 256);
    float* candDist = (float*)(ws + 1024);
    float* S0       = (float*)(ws + 2048);                 // 7168 B
    unsigned short* VcB = (unsigned short*)(ws + 245760);  // 114688 B (bf16)
    unsigned short* Y   = (unsigned short*)(ws + 475136);  // 1835008 B (Y2 layout)
    unsigned short* WkT = (unsigned short*)(ws + 2310144); // 524288 B
    unsigned short* WvT = (unsigned short*)(ws + 2834432); // 524288 B
    unsigned short* X2  = (unsigned short*)(ws + 3358720); // 16777216 B
    float* gBias        = (float*)(ws + 20135936);         // 3145728 B
    int useX2   = (ws_size >= (size_t)3358720 + 16777216) ? 1 : 0;
    int useBias = (ws_size >= (size_t)20135936 + 3145728) ? 1 : 0;

    k_pre<<<145, 256, 0, stream>>>(dist, speed, Wk, Wv, Kp, candIdx, candDist, WkT, WvT);
    int biasBase = 384 + (useX2 ? 512 : 0);
    int midBlocks = biasBase + (useBias ? 64 : 0);
    k_mid<<<midBlocks, 256, 0, stream>>>(X, dist, WkT, bk, WvT, bv, Wq, bq, Weq, beq,
                                         Wd1, bd1, Wd2, bd2, Kp, candIdx, candDist,
                                         VcB, S0, Y, X2, gBias, biasBase);
    k_attn<<<CB * (CN / RB), 512, 0, stream>>>(X, dist, mask, Wd1, bd1, Wd2, bd2, lng, lnb,
                                               Kp, candIdx, candDist, VcB, S0, Y,
                                               X2, useX2, gBias, useBias, out);
}